// Round 2
// baseline (482.136 us; speedup 1.0000x reference)
//
#include <hip/hip_runtime.h>
#include <math.h>

// Problem constants
#define BB   4
#define SS   256
#define VV   64
#define LP1  11
#define HH   128
#define NHH  8
#define DHH  16
#define NLL  3
#define BSZ  1024   // BB*SS

typedef unsigned short u16;
typedef unsigned int   u32;
typedef __attribute__((ext_vector_type(8))) short s16x8;   // 8 bf16 (4 VGPR)
typedef __attribute__((ext_vector_type(4))) float f32x4;   // MFMA acc

__device__ __forceinline__ float bfbits2f(u32 hi16) {
    u32 i = hi16 << 16; float f; __builtin_memcpy(&f, &i, 4); return f;
}
__device__ __forceinline__ u16 f2bf(float f) {
    u32 i; __builtin_memcpy(&i, &f, 4);
    return (u16)((i + 0x7fffu + ((i >> 16) & 1u)) >> 16);
}
__device__ __forceinline__ u16 f2bf_trunc(float f) {
    u32 i; __builtin_memcpy(&i, &f, 4);
    return (u16)(i >> 16);
}
__device__ __forceinline__ float ldf(const void* p, size_t i, int isbf) {
    if (isbf) return bfbits2f(((const u16*)p)[i]);
    return ((const float*)p)[i];
}
__device__ __forceinline__ float4 ld4(const void* p, size_t i, int isbf) {
    float4 v;
    if (isbf) {
        uint2 u = *(const uint2*)((const u16*)p + i);
        v.x = bfbits2f(u.x & 0xffffu); v.y = bfbits2f(u.x >> 16);
        v.z = bfbits2f(u.y & 0xffffu); v.w = bfbits2f(u.y >> 16);
    } else {
        v = *(const float4*)((const float*)p + i);
    }
    return v;
}

// ---------- kernel S: global dtype sniff on mech_W (random, nonzero) -------
__global__ __launch_bounds__(64) void k_sniff(const u16* __restrict__ probe,
                                              int* __restrict__ flags) {
    if (threadIdx.x == 0) {
        int wild = 0;
        for (int j = 0; j < 256; j++) {
            float v = bfbits2f(probe[j]);
            if (!(fabsf(v) < 1e8f)) wild = 1;
        }
        flags[0] = wild ? 0 : 1;   // 1 = bf16 storage (inputs exact; bf16 output)
    }
}

// ---------------- kernel 1: adj = sigmoid(adjacency_logits) ----------------
__global__ __launch_bounds__(256) void k_adj(const void* __restrict__ logits,
                                             float* __restrict__ adj,
                                             const int* __restrict__ flags) {
    int isbf = flags[0];
    int i = blockIdx.x * 256 + threadIdx.x;
    if (i < VV * VV * LP1) {
        float v = ldf(logits, i, isbf);
        adj[i] = 1.f / (1.f + expf(-v));
    }
}

// ---------------- kernel 0b: fold Wo into output head ----------------------
__global__ __launch_bounds__(128) void k_fuse(const void* __restrict__ Wo,
                                              const void* __restrict__ outW,
                                              const void* __restrict__ bo,
                                              const void* __restrict__ outb,
                                              float* __restrict__ wfused,
                                              float* __restrict__ bfused,
                                              const int* __restrict__ flags) {
    int isbf = flags[0];
    int v = blockIdx.x; int h = threadIdx.x;
    __shared__ float ow[HH];
    __shared__ float red[HH];
    ow[h] = ldf(outW, (size_t)v * HH + h, isbf);
    __syncthreads();
    size_t wb = ((size_t)v * HH + h) * HH;
    float acc = 0.f;
    #pragma unroll 8
    for (int k = 0; k < HH; k++) acc += ldf(Wo, wb + k, isbf) * ow[k];
    wfused[v * HH + h] = acc;
    red[h] = ldf(bo, (size_t)v * HH + h, isbf) * ow[h];
    __syncthreads();
    for (int s = 64; s > 0; s >>= 1) { if (h < s) red[h] += red[h + s]; __syncthreads(); }
    if (h == 0) bfused[v] = red[0] + ldf(outb, v, isbf);
}

// ---------------- kernel 2: causal input -> zh/zl bf16 hi/lo ---------------
__global__ __launch_bounds__(256) void k_causal(const void* __restrict__ x,
                                                const float* __restrict__ adj,
                                                const void* __restrict__ var_emb,
                                                const void* __restrict__ temp_emb,
                                                u16* __restrict__ zh,
                                                u16* __restrict__ zl,
                                                const int* __restrict__ flags) {
    __shared__ float xl[LP1][VV];            // 2.75 KB
    __shared__ float A_sh[VV][VV + 1];       // 16.25 KB
    __shared__ float Blp_sh[VV * LP1 * 4];   // 11 KB partials
    __shared__ float Bl_sh[VV][12];          // 3 KB
    int isbf = flags[0];
    int tid = threadIdx.x;
    int bt = blockIdx.x; int b = bt >> 8; int t = bt & 255;

    for (int p = tid; p < LP1 * VV; p += 256) {
        int l = p >> 6, s = p & 63; int tt = t - l;
        xl[l][s] = (tt >= 0) ? ldf(x, (size_t)(b * SS + tt) * VV + s, isbf) : 0.f;
    }
    __syncthreads();

    // fused A + Bl-partial pass: thread has fixed i, 16 s values (s = sg + 4k)
    {
        int i = tid & 63, sg = tid >> 6;
        float blp[LP1];
        #pragma unroll
        for (int l = 0; l < LP1; l++) blp[l] = 0.f;
        for (int k = 0; k < 16; k++) {
            int s = sg + k * 4;
            const float* ap = adj + (s * VV + i) * LP1;
            float a = 0.f;
            #pragma unroll
            for (int l = 0; l < LP1; l++) {
                float pr = xl[l][s] * ap[l];
                a += pr; blp[l] += pr;
            }
            A_sh[i][s] = a;
        }
        #pragma unroll
        for (int l = 0; l < LP1; l++)
            Blp_sh[(i * LP1 + l) * 4 + sg] = blp[l];
    }
    __syncthreads();
    for (int p = tid; p < VV * LP1; p += 256) {
        int i = p / LP1, l = p - i * LP1;
        const float* q = &Blp_sh[(i * LP1 + l) * 4];
        Bl_sh[i][l] = (q[0] + q[1]) + (q[2] + q[3]);
    }
    __syncthreads();

    int h0 = (tid & 31) * 4;   // 4 h-values
    int ig = tid >> 5;         // 8 i-values
    float acc[8][4];
    #pragma unroll
    for (int ii = 0; ii < 8; ii++)
        #pragma unroll
        for (int j = 0; j < 4; j++) acc[ii][j] = 0.f;

    if (isbf) {
        for (int s = 0; s < VV; s++) {
            float4 v4 = ld4(var_emb, (size_t)s * HH + h0, 1);
            #pragma unroll
            for (int ii = 0; ii < 8; ii++) {
                float a = A_sh[ig * 8 + ii][s];
                acc[ii][0] += a * v4.x; acc[ii][1] += a * v4.y;
                acc[ii][2] += a * v4.z; acc[ii][3] += a * v4.w;
            }
        }
        #pragma unroll
        for (int l = 0; l < LP1; l++) {
            float4 t4 = ld4(temp_emb, (size_t)l * HH + h0, 1);
            #pragma unroll
            for (int ii = 0; ii < 8; ii++) {
                float bl = Bl_sh[ig * 8 + ii][l];
                acc[ii][0] += bl * t4.x; acc[ii][1] += bl * t4.y;
                acc[ii][2] += bl * t4.z; acc[ii][3] += bl * t4.w;
            }
        }
    } else {
        for (int s = 0; s < VV; s++) {
            float4 v4 = ld4(var_emb, (size_t)s * HH + h0, 0);
            #pragma unroll
            for (int ii = 0; ii < 8; ii++) {
                float a = A_sh[ig * 8 + ii][s];
                acc[ii][0] += a * v4.x; acc[ii][1] += a * v4.y;
                acc[ii][2] += a * v4.z; acc[ii][3] += a * v4.w;
            }
        }
        #pragma unroll
        for (int l = 0; l < LP1; l++) {
            float4 t4 = ld4(temp_emb, (size_t)l * HH + h0, 0);
            #pragma unroll
            for (int ii = 0; ii < 8; ii++) {
                float bl = Bl_sh[ig * 8 + ii][l];
                acc[ii][0] += bl * t4.x; acc[ii][1] += bl * t4.y;
                acc[ii][2] += bl * t4.z; acc[ii][3] += bl * t4.w;
            }
        }
    }

    #pragma unroll
    for (int ii = 0; ii < 8; ii++) {
        int i = ig * 8 + ii;
        size_t idx = ((size_t)i * BSZ + bt) * HH + h0;
        u16 h0_ = f2bf(acc[ii][0]), h1_ = f2bf(acc[ii][1]);
        u16 h2_ = f2bf(acc[ii][2]), h3_ = f2bf(acc[ii][3]);
        uint2 hw, lw;
        hw.x = (u32)h0_ | ((u32)h1_ << 16); hw.y = (u32)h2_ | ((u32)h3_ << 16);
        lw.x = (u32)f2bf(acc[ii][0] - bfbits2f(h0_)) | ((u32)f2bf(acc[ii][1] - bfbits2f(h1_)) << 16);
        lw.y = (u32)f2bf(acc[ii][2] - bfbits2f(h2_)) | ((u32)f2bf(acc[ii][3] - bfbits2f(h3_)) << 16);
        *(uint2*)&zh[idx] = hw;
        *(uint2*)&zl[idx] = lw;
    }
}

// ---------------- kernel Wp: merged weight pre-transpose (1 dispatch) ------
struct WPack {
    const void* src[4];
    u16* dh[4];
    u16* dl[4];
};
#define TP 136   // u16 pitch
__global__ __launch_bounds__(256) void k_wprep(WPack wp,
                                               const int* __restrict__ flags) {
    int isbf = flags[0];
    int mat = blockIdx.x;
    int seg = (mat < 192) ? 0 : 1 + ((mat - 192) >> 6);
    int rel = (mat < 192) ? mat : ((mat - 192) & 63);
    const void* raw = wp.src[seg];
    u16* Wh = wp.dh[seg];
    u16* Wl = wp.dl[seg];
    int tid = threadIdx.x;
    size_t src = (size_t)rel * (HH * HH);
    if (isbf) {
        __shared__ u16 tile[HH * TP];   // 34 KB
        const uint4* sp = (const uint4*)((const u16*)raw + src);
        #pragma unroll
        for (int u = 0; u < 8; u++) {
            int p = u * 256 + tid;
            int h = p >> 4, k8 = (p & 15) * 8;
            int k8s = k8 ^ ((((u32)h >> 3) & 15) * 8);
            *(uint4*)&tile[h * TP + k8s] = sp[p];
        }
        __syncthreads();
        #pragma unroll
        for (int u = 0; u < 8; u++) {
            int p = u * 256 + tid;
            int kcol = p >> 4, h8 = (p & 15) * 8;
            u16 vals[8];
            #pragma unroll
            for (int j = 0; j < 8; j++) {
                int h = h8 + j;
                int ks = kcol ^ ((((u32)h >> 3) & 15) * 8);
                vals[j] = tile[h * TP + ks];
            }
            uint4 pk;
            pk.x = (u32)vals[0] | ((u32)vals[1] << 16);
            pk.y = (u32)vals[2] | ((u32)vals[3] << 16);
            pk.z = (u32)vals[4] | ((u32)vals[5] << 16);
            pk.w = (u32)vals[6] | ((u32)vals[7] << 16);
            *(uint4*)&Wh[src + (size_t)kcol * HH + h8] = pk;
        }
    } else {
        int kcol = tid >> 1, h0 = (tid & 1) * 64;
        size_t dst = src + (size_t)kcol * HH;
        for (int i = 0; i < 64; i++) {
            int h = h0 + i;
            float w = ldf(raw, src + (size_t)h * HH + kcol, 0);
            u16 hi = f2bf(w);
            Wh[dst + h] = hi;
            Wl[dst + h] = f2bf(w - bfbits2f(hi));
        }
    }
}

// ---------------- kernel M: fused mech x3 + QKV, LDS-resident z ------------
// R15: + XCD-bijective swizzle (all 16 tiles of a v on one XCD -> weights
//   fetched once per XCD, FETCH 116->~50 MB), + cross-barrier weight prefetch
//   (reg double-set; 2nd barrier = lgkmcnt(0)+raw s_barrier so vm loads stay
//   in flight), + 52 KB LDS (drop Bl_s; !wexact runs 2 passes over one
//   buffer) -> 3 blocks/CU, + coalesced V store via LDS transpose (Bh_s is
//   dead in the last layer).
#define PZq 136  // u16 pitch, 16B-aligned rows, bank stride 4 (2-way = free)
#define PB  72   // u16 pitch for B chunk (bank stride 4)
__global__ __launch_bounds__(256, 3) void k_mega(
    const u16* __restrict__ zh, const u16* __restrict__ zl,
    const u16* __restrict__ WmH, const u16* __restrict__ WmL,
    const u16* __restrict__ WqH, const u16* __restrict__ WqL,
    const u16* __restrict__ WkH, const u16* __restrict__ WkL,
    const u16* __restrict__ WvH, const u16* __restrict__ WvL,
    const void* __restrict__ mechb,
    const void* __restrict__ lng, const void* __restrict__ lnb,
    const void* __restrict__ bq, const void* __restrict__ bk,
    const void* __restrict__ bv,
    u16* __restrict__ Qh, u16* __restrict__ Ql,
    u16* __restrict__ Ko, u16* __restrict__ Vt,
    const int* __restrict__ flags)
{
    __shared__ u16 Az_h[64 * PZq];   // 17 KB
    __shared__ u16 Az_l[64 * PZq];   // 17 KB
    __shared__ u16 Bh_s[128 * PB];   // 18 KB; doubles as V-transpose buffer
    u16* Vt_sh = Bh_s;
    int isbf = flags[0];
    int wexact = isbf;
    int tid = threadIdx.x;
    // XCD-bijective swizzle: bid%8 = XCD (dispatch round-robin heuristic).
    // v in [xcd*8, xcd*8+8), all 16 tiles of a v on the same XCD.
    int bid = blockIdx.x;
    int xcd = bid & 7, idx = bid >> 3;
    int v = xcd * 8 + (idx >> 4);
    int tile = idx & 15;
    int wave = tid >> 6, lane = tid & 63;
    int quad = lane >> 4, l15 = lane & 15;
    int m0 = wave * 16;

    // stage the z tile once (hi/lo), coalesced
    size_t zbase = ((size_t)v * BSZ + (size_t)tile * 64) * HH;
    #pragma unroll
    for (int u = 0; u < 4; u++) {
        int p = u * 256 + tid;
        int row = p >> 4, k8 = (p & 15) * 8;
        *(uint4*)&Az_h[row * PZq + k8] = *(const uint4*)&zh[zbase + (size_t)row * HH + k8];
        *(uint4*)&Az_l[row * PZq + k8] = *(const uint4*)&zl[zbase + (size_t)row * HH + k8];
    }

    int shift = wexact ? 1 : 2;       // chunks per layer: 2 (hi) or 4 (hi+lo)
    int PER = 1 << shift;
    int NCH = 6 << shift;
    int n0 = tid >> 3;
    int k8u = (tid & 7) * 8;

    auto wsrc = [&](int ch) -> const u16* {
        int li = ch >> shift;
        int sub = ch & (PER - 1);
        int cc = sub & 1;
        int lo = sub >> 1;
        const u16* p; size_t wb;
        if (li < 3)       { p = lo ? WmL : WmH; wb = (size_t)(v * NLL + li) * (HH * HH); }
        else if (li == 3) { p = lo ? WqL : WqH; wb = (size_t)v * (HH * HH); }
        else if (li == 4) { p = lo ? WkL : WkH; wb = (size_t)v * (HH * HH); }
        else              { p = lo ? WvL : WvH; wb = (size_t)v * (HH * HH); }
        return p + wb + cc * 64;
    };

    f32x4 acc[8];

    auto epilogue = [&](int li) {
        float bcol[8], gcol[8], b2col[8];
        #pragma unroll
        for (int nt = 0; nt < 8; nt++) {
            int col = nt * 16 + l15;
            if (li < 3) {
                size_t pb = (size_t)v * (NLL * HH) + (size_t)li * HH + col;
                bcol[nt]  = ldf(mechb, pb, isbf);
                gcol[nt]  = ldf(lng, pb, isbf);
                b2col[nt] = ldf(lnb, pb, isbf);
            } else {
                const void* bp = (li == 3) ? bq : (li == 4) ? bk : bv;
                bcol[nt] = ldf(bp, (size_t)v * HH + col, isbf);
            }
        }
        if (li == 5) __syncthreads();   // claim Bh_s as V-transpose buffer
        #pragma unroll
        for (int r = 0; r < 4; r++) {
            float vals[8];
            float sum = 0.f, sq = 0.f;
            #pragma unroll
            for (int nt = 0; nt < 8; nt++) {
                float val = acc[nt][r] + bcol[nt];
                vals[nt] = val; sum += val; sq += val * val;
            }
            int rloc = m0 + quad * 4 + r;
            if (li < 3) {
                #pragma unroll
                for (int m = 1; m < 16; m <<= 1) {
                    sum += __shfl_xor(sum, m);
                    sq  += __shfl_xor(sq, m);
                }
                float mean = sum * (1.f / HH);
                float var  = sq * (1.f / HH) - mean * mean;
                float rstd = rsqrtf(var + 1e-5f);
                #pragma unroll
                for (int nt = 0; nt < 8; nt++) {
                    float y = (vals[nt] - mean) * rstd * gcol[nt] + b2col[nt];
                    y = 0.5f * y * (1.f + erff(y * 0.70710678118654752f));
                    u16 hi = f2bf(y);
                    Az_h[rloc * PZq + nt * 16 + l15] = hi;
                    Az_l[rloc * PZq + nt * 16 + l15] = f2bf(y - bfbits2f(hi));
                }
            } else if (li == 3) {       // Q hi/lo
                int row = tile * 64 + rloc;
                size_t ob = ((size_t)v * BSZ + row) * HH;
                #pragma unroll
                for (int nt = 0; nt < 8; nt++) {
                    u16 hi = f2bf(vals[nt]);
                    Qh[ob + nt * 16 + l15] = hi;
                    Ql[ob + nt * 16 + l15] = f2bf(vals[nt] - bfbits2f(hi));
                }
            } else if (li == 4) {       // K natural bf16
                int row = tile * 64 + rloc;
                size_t ob = ((size_t)v * BSZ + row) * HH;
                #pragma unroll
                for (int nt = 0; nt < 8; nt++)
                    Ko[ob + nt * 16 + l15] = f2bf(vals[nt]);
            } else {                    // V: stage transposed tile in LDS
                #pragma unroll
                for (int nt = 0; nt < 8; nt++)
                    Vt_sh[(nt * 16 + l15) * PB + rloc] = f2bf(vals[nt]);
            }
        }
        if (li == 5) {
            __syncthreads();
            // coalesced V store: 128 (head,d) rows x 64 tt, full 64B lines
            int col = tid >> 1, half = tid & 1;
            int n = col >> 4, d = col & 15;
            int bb = tile >> 2, t0 = (tile & 3) * 64;
            size_t dst = (((size_t)(v * BB + bb) * NHH + n) * DHH + d) * SS + t0 + half * 32;
            #pragma unroll
            for (int j = 0; j < 4; j++)
                *(uint4*)&Vt[dst + j * 8] = *(const uint4*)&Vt_sh[col * PB + half * 32 + j * 8];
        }
    };

#define MEGA_STEP(CH, STG, PRF)                                              \
  {                                                                          \
    int ch_ = (CH);                                                          \
    __syncthreads();  /* barrier A: full drain; prefetched regs needed now */ \
    _Pragma("unroll")                                                        \
    for (int u = 0; u < 4; u++)                                              \
        *(uint4*)&Bh_s[(u * 32 + n0) * PB + k8u] = STG[u];                   \
    if (ch_ + 1 < NCH) {                                                     \
        const u16* s_ = wsrc(ch_ + 1);                                       \
        _Pragma("unroll")                                                    \
        for (int u = 0; u < 4; u++)                                          \
            PRF[u] = *(const uint4*)&s_[(size_t)(u * 32 + n0) * HH + k8u];   \
    }                                                                        \
    /* barrier B: ds_writes visible, but prefetch vm loads stay in flight */ \
    asm volatile("s_waitcnt lgkmcnt(0)" ::: "memory");                       \
    __builtin_amdgcn_s_barrier();                                            \
    {                                                                        \
        int sub_ = ch_ & (PER - 1);                                          \
        int li_ = ch_ >> shift;                                              \
        int cc_ = sub_ & 1, lo_ = sub_ >> 1;                                 \
        if (sub_ == 0) {                                                     \
            _Pragma("unroll")                                                \
            for (int nt = 0; nt < 8; nt++) {                                 \
                f32x4 zz = {0.f, 0.f, 0.f, 0.f};                             \
                acc[nt] = zz;                                                \
            }                                                                \
        }                                                                    \
        _Pragma("unroll")                                                    \
        for (int kk = 0; kk < 2; kk++) {                                     \
            int ka = cc_ * 64 + kk * 32 + quad * 8;                          \
            int kb = kk * 32 + quad * 8;                                     \
            s16x8 ah = *(const s16x8*)&Az_h[(m0 + l15) * PZq + ka];          \
            if (!lo_) {                                                      \
                s16x8 al = *(const s16x8*)&Az_l[(m0 + l15) * PZq + ka];      \
                _Pragma("unroll")                                            \
                for (int nt = 0; nt < 8; nt++) {                             \
                    s16x8 bh = *(const s16x8*)&Bh_s[(nt * 16 + l15) * PB + kb]; \
                    acc[nt] = __builtin_amdgcn_mfma_f32_16x16x32_bf16(ah, bh, acc[nt], 0, 0, 0); \
                    acc[nt] = __builtin_amdgcn_mfma_f32_16x16x32_bf16(al, bh, acc[nt], 0, 0, 0); \
                }                                                            \
            } else {                                                         \
                _Pragma("unroll")                                            \
                for (int nt = 0; nt < 8; nt++) {                             \
                    s16x8 bl = *(const s16x8*)&Bh_s[(nt * 16 + l15) * PB + kb]; \
                    acc[nt] = __builtin_amdgcn_mfma_f32_16x16x32_bf16(ah, bl, acc[nt], 0, 0, 0); \
                }                                                            \
            }                                                                \
        }                                                                    \
        if (sub_ == PER - 1) epilogue(li_);                                  \
    }                                                                        \
  }

    uint4 pa[4], pb[4];
    {
        const u16* s0 = wsrc(0);
        #pragma unroll
        for (int u = 0; u < 4; u++)
            pa[u] = *(const uint4*)&s0[(size_t)(u * 32 + n0) * HH + k8u];
    }
    for (int ch = 0; ch < NCH; ch += 2) {
        MEGA_STEP(ch, pa, pb);
        MEGA_STEP(ch + 1, pb, pa);
    }
#undef MEGA_STEP
}

// ---------------- kernel 5: MFMA attention, 4 waves / (v,b,head) -----------
#define LDW 40
__global__ __launch_bounds__(256) void k_attn2(const u16* __restrict__ Qh,
                                               const u16* __restrict__ Ql,
                                               const u16* __restrict__ K16,
                                               const u16* __restrict__ Vt,
                                               float* __restrict__ O) {
    __shared__ u16 Kp_sh[SS * LDW];        // 20 KB: cols 0-15 = K, 16-31 = K dup
    __shared__ u16 Vt_sh[DHH * 264];       // 8.25 KB
    __shared__ u16 P_sh[4][16 * LDW];      // per-wave P tile
    int tid = threadIdx.x;
    int wave = tid >> 6, lane = tid & 63;
    int quad = lane >> 4, l15 = lane & 15;
    int bn = blockIdx.x, v = blockIdx.y;
    int b = bn >> 3, n = bn & 7;
    size_t qkbase = ((size_t)v * BSZ + b * SS) * HH + n * DHH;
    size_t vtbase = ((size_t)(v * BB + b) * NHH + n) * DHH * SS;

    {
        int row = tid;
        uint4 k0 = *(const uint4*)&K16[qkbase + (size_t)row * HH];
        uint4 k1 = *(const uint4*)&K16[qkbase + (size_t)row * HH + 8];
        *(uint4*)&Kp_sh[row * LDW + 0]  = k0;
        *(uint4*)&Kp_sh[row * LDW + 8]  = k1;
        *(uint4*)&Kp_sh[row * LDW + 16] = k0;
        *(uint4*)&Kp_sh[row * LDW + 24] = k1;
    }
    #pragma unroll
    for (int u = 0; u < 2; u++) {
        int p = u * 256 + tid;
        int d = p >> 5, su = (p & 31) * 8;
        *(uint4*)&Vt_sh[d * 264 + su] = *(const uint4*)&Vt[vtbase + (size_t)d * SS + su];
    }
    __syncthreads();

    s16x8 ones;
    #pragma unroll
    for (int i = 0; i < 8; i++) ones[i] = (short)0x3F80;

    for (int mt = wave * 4; mt < wave * 4 + 4; mt++) {
        const u16* Qsrc = (quad < 2) ? Qh : Ql;
        s16x8 aq = *(const s16x8*)&Qsrc[qkbase + (size_t)(mt * 16 + l15) * HH + (quad & 1) * 8];
        f32x4 oacc = {0.f, 0.f, 0.f, 0.f};
        f32x4 lacc = {0.f, 0.f, 0.f, 0.f};
        for (int jt2 = 0; jt2 < 8; jt2++) {
            #pragma unroll
            for (int sub = 0; sub < 2; sub++) {
                int jt = jt2 * 2 + sub;
                s16x8 bk = *(const s16x8*)&Kp_sh[(jt * 16 + l15) * LDW + quad * 8];
                f32x4 s = {0.f, 0.f, 0.f, 0.f};
                s = __builtin_amdgcn_mfma_f32_16x16x32_bf16(aq, bk, s, 0, 0, 0);
                #pragma unroll
                for (int r = 0; r < 4; r++) {
                    float p = __expf(s[r] * 0.25f);
                    P_sh[wave][(quad * 4 + r) * LDW + sub * 16 + l15] = f2bf_trunc(p);
                }
            }
            s16x8 ap = *(const s16x8*)&P_sh[wave][l15 * LDW + quad * 8];
            s16x8 bv = *(const s16x8*)&Vt_sh[l15 * 264 + jt2 * 32 + quad * 8];
            oacc = __builtin_amdgcn_mfma_f32_16x16x32_bf16(ap, bv, oacc, 0, 0, 0);
            lacc = __builtin_amdgcn_mfma_f32_16x16x32_bf16(ap, ones, lacc, 0, 0, 0);
        }
        #pragma unroll
        for (int r = 0; r < 4; r++) {
            float val = oacc[r] / lacc[r];
            O[((size_t)v * BSZ + b * SS + mt * 16 + quad * 4 + r) * HH + n * DHH + l15] = val;
        }
    }
}

// ---------------- kernel 6: fused output head (coalesced) ------------------
__global__ __launch_bounds__(256) void k_final(const float* __restrict__ o,
                                               const float* __restrict__ wfused,
                                               const float* __restrict__ bfused,
                                               void* __restrict__ out,
                                               const int* __restrict__ flags) {
    __shared__ float wf[HH];
    int isbf = flags[0];
    int tid = threadIdx.x; int b = blockIdx.x; int v = blockIdx.y;
    if (tid < HH) wf[tid] = wfused[v * HH + tid];
    __syncthreads();
    int rg = tid >> 3;
    int l8 = tid & 7;
    float4 w0 = *(const float4*)&wf[l8 * 16];
    float4 w1 = *(const float4*)&wf[l8 * 16 + 4];
    float4 w2 = *(const float4*)&wf[l8 * 16 + 8];
    float4 w3 = *(const float4*)&wf[l8 * 16 + 12];
    float bv = bfused[v];
    #pragma unroll
    for (int pass = 0; pass < 8; pass++) {
        int bt = b * SS + pass * 32 + rg;
        const float4* orow = (const float4*)(o + ((size_t)v * BSZ + bt) * HH + l8 * 16);
        float4 a0 = orow[0], a1 = orow[1], a2 = orow[2], a3 = orow[3];
        float acc = a0.x * w0.x + a0.y * w0.y + a0.z * w0.z + a0.w * w0.w
                  + a1.x * w1.x + a1.y * w1.y + a1.z * w1.z + a1.w * w1.w
                  + a2.x * w2.x + a2.y * w2.y + a2.z * w2.z + a2.w * w2.w
                  + a3.x * w3.x + a3.y * w3.y + a3.z * w3.z + a3.w * w3.w;
        acc += __shfl_xor(acc, 1);
        acc += __shfl_xor(acc, 2);
        acc += __shfl_xor(acc, 4);
        if (l8 == 0) {
            float pred = acc + bv;
            size_t oi = (size_t)bt * VV + v;
            if (isbf) ((u16*)out)[oi] = f2bf(pred);
            else      ((float*)out)[oi] = pred;
        }
    }
}

extern "C" void kernel_launch(void* const* d_in, const int* in_sizes, int n_in,
                              void* d_out, int out_size, void* d_ws, size_t ws_size,
                              hipStream_t stream) {
    (void)out_size; (void)ws_size;

    // ---- resolve input permutation from in_sizes (host-side, capture-safe) ----
    static const int dict_sizes[18]  = {65536,45056,8192,1408,3145728,24576,24576,24576,
                                        1048576,1048576,1048576,1048576,8192,8192,8192,8192,8192,64};
    static const int alpha_sizes[18] = {1048576,1048576,1048576,1048576,45056,8192,8192,8192,
                                        8192,24576,24576,3145728,24576,8192,64,1408,8192,65536};
    static const int alpha_pos[18]   = {17,4,16,15,11,12,10,9,2,0,3,1,7,5,8,6,13,14};
    static const int alpha_logical[18] = {9,11,8,10,1,13,15,12,14,7,6,4,5,16,17,3,2,0};

    const void* in[18];
    bool is_dict = (n_in == 18), is_alpha = (n_in == 18);
    for (int i = 0; i < 18 && i < n_in; i++) {
        if (in_sizes[i] != dict_sizes[i])  is_dict = false;
        if (in_sizes[i] != alpha_sizes[i]) is_alpha = false;
    }
    if (is_dict) {
        for (int i = 0; i < 18; i++) in[i] = d_in[i];
    } else if (is_alpha) {
        for (int i = 0; i < 18; i++) in[i] = d_in[alpha_pos[i]];
    } else {
        bool used[18] = {false};
        for (int a = 0; a < 18; a++) {
            int lg = alpha_logical[a];
            for (int i = 0; i < n_in && i < 18; i++) {
                if (!used[i] && in_sizes[i] == dict_sizes[lg]) {
                    in[lg] = d_in[i]; used[i] = true; break;
                }
            }
        }
    }

    const void* x        = in[0];
    const void* adjl     = in[1];
    const void* var_emb  = in[2];
    const void* temp_emb = in[3];
    const void* mechW    = in[4];
    const void* mechb    = in[5];
    const void* lng      = in[6];
    const void* lnb      = in[7];
    const void* Wq       = in[8];
    const void* Wk       = in[9];
    const void* Wv       = in[10];
    const void* Wo       = in[11];
    const void* bq       = in[12];
    const void* bk       = in[13];
    const void* bv       = in[14];
    const void* bo       = in[15];
    const void* outW     = in[16];
    const void* outb     = in[17];

    // workspace (f32-unit offsets), total 126.0 MB
    float* ws     = (float*)d_ws;
    int*   flags  = (int*)ws;                   // 32 f
    float* adj    = ws + 32;                    // 45056
    float* wfused = ws + 45088;                 // 8192
    float* bfused = ws + 53280;                 // 64 (to 53376)
    u16*   zhA    = (u16*)(ws + 53376);         // -> 4247680  (causal z hi)
    u16*   zlA    = (u16*)(ws + 4247680);       // -> 8441984  (causal z lo)
    u16*   zhB    = (u16*)(ws + 8441984);       // -> 12636288 (Q hi)
    u16*   zlB    = (u16*)(ws + 12636288);      // -> 16830592 (Q lo)
    float* Obuf   = ws + 53376;                 // overlays zhA+zlA (dead by attn)
    u16*   K16    = (u16*)(ws + 16830592);      // -> 21024896
    u16*   Vt16   = (u16*)(ws + 21024896);      // -> 25219200
    u16*   WtmH   = (u16*)(ws + 25219200);      // -> 26792064
    u16*   WtmL   = (u16*)(ws + 26792064);      // -> 28364928
    u16*   WtqH   = (u16*)(ws + 28364928);      // -> 28889216
    u16*   WtqL   = (u16*)(ws + 28889216);      // -> 29413504
    u16*   WtkH   = (u16*)(ws + 29413504);      // -> 29937792
    u16*   WtkL   = (u16*)(ws + 29937792);      // -> 30462080
    u16*   WtvH   = (u16*)(ws + 30462080);      // -> 30986368
    u16*   WtvL   = (u16*)(ws + 30986368);      // -> 31510656

    k_sniff <<<dim3(1),    dim3(64),  0, stream>>>((const u16*)mechW, flags);
    k_adj   <<<dim3(176),  dim3(256), 0, stream>>>(adjl, adj, flags);
    k_fuse  <<<dim3(64),   dim3(128), 0, stream>>>(Wo, outW, bo, outb, wfused, bfused, flags);
    k_causal<<<dim3(BSZ),  dim3(256), 0, stream>>>(x, adj, var_emb, temp_emb, zhA, zlA, flags);

    WPack wp;
    wp.src[0] = mechW; wp.dh[0] = WtmH; wp.dl[0] = WtmL;
    wp.src[1] = Wq;    wp.dh[1] = WtqH; wp.dl[1] = WtqL;
    wp.src[2] = Wk;    wp.dh[2] = WtkH; wp.dl[2] = WtkL;
    wp.src[3] = Wv;    wp.dh[3] = WtvH; wp.dl[3] = WtvL;
    k_wprep <<<dim3(384),  dim3(256), 0, stream>>>(wp, flags);

    // fused mech x3 + QKV: z resident in LDS, XCD-swizzled, weight-prefetched
    k_mega<<<dim3(1024), dim3(256), 0, stream>>>(
            zhA, zlA,
            WtmH, WtmL, WtqH, WtqL, WtkH, WtkL, WtvH, WtvL,
            mechb, lng, lnb, bq, bk, bv,
            zhB, zlB, K16, Vt16, flags);

    k_attn2 <<<dim3(BB * NHH, VV), dim3(256), 0, stream>>>(zhB, zlB, K16, Vt16, Obuf);
    k_final <<<dim3(BB, VV), dim3(256), 0, stream>>>(Obuf, wfused, bfused, d_out, flags);
}

// Round 3
// 420.547 us; speedup vs baseline: 1.1464x; 1.1464x over previous
//
#include <hip/hip_runtime.h>
#include <math.h>

// Problem constants
#define BB   4
#define SS   256
#define VV   64
#define LP1  11
#define HH   128
#define NHH  8
#define DHH  16
#define NLL  3
#define BSZ  1024   // BB*SS

typedef unsigned short u16;
typedef unsigned int   u32;
typedef __attribute__((ext_vector_type(8))) short s16x8;   // 8 bf16 (4 VGPR)
typedef __attribute__((ext_vector_type(4))) float f32x4;   // MFMA acc

__device__ __forceinline__ float bfbits2f(u32 hi16) {
    u32 i = hi16 << 16; float f; __builtin_memcpy(&f, &i, 4); return f;
}
__device__ __forceinline__ u16 f2bf(float f) {
    u32 i; __builtin_memcpy(&i, &f, 4);
    return (u16)((i + 0x7fffu + ((i >> 16) & 1u)) >> 16);
}
__device__ __forceinline__ u16 f2bf_trunc(float f) {
    u32 i; __builtin_memcpy(&i, &f, 4);
    return (u16)(i >> 16);
}
__device__ __forceinline__ float ldf(const void* p, size_t i, int isbf) {
    if (isbf) return bfbits2f(((const u16*)p)[i]);
    return ((const float*)p)[i];
}
__device__ __forceinline__ float4 ld4(const void* p, size_t i, int isbf) {
    float4 v;
    if (isbf) {
        uint2 u = *(const uint2*)((const u16*)p + i);
        v.x = bfbits2f(u.x & 0xffffu); v.y = bfbits2f(u.x >> 16);
        v.z = bfbits2f(u.y & 0xffffu); v.w = bfbits2f(u.y >> 16);
    } else {
        v = *(const float4*)((const float*)p + i);
    }
    return v;
}
// async global->LDS, 16B per lane. LDS dest = wave-uniform base + lane*16.
__device__ __forceinline__ void gll16(const u16* g, u16* l) {
    __builtin_amdgcn_global_load_lds(
        (const __attribute__((address_space(1))) void*)g,
        (__attribute__((address_space(3))) void*)l, 16, 0, 0);
}

// ---------- kernel S: global dtype sniff on mech_W (random, nonzero) -------
__global__ __launch_bounds__(64) void k_sniff(const u16* __restrict__ probe,
                                              int* __restrict__ flags) {
    if (threadIdx.x == 0) {
        int wild = 0;
        for (int j = 0; j < 256; j++) {
            float v = bfbits2f(probe[j]);
            if (!(fabsf(v) < 1e8f)) wild = 1;
        }
        flags[0] = wild ? 0 : 1;   // 1 = bf16 storage (inputs exact; bf16 output)
    }
}

// ---------------- kernel 1: adj = sigmoid(adjacency_logits) ----------------
__global__ __launch_bounds__(256) void k_adj(const void* __restrict__ logits,
                                             float* __restrict__ adj,
                                             const int* __restrict__ flags) {
    int isbf = flags[0];
    int i = blockIdx.x * 256 + threadIdx.x;
    if (i < VV * VV * LP1) {
        float v = ldf(logits, i, isbf);
        adj[i] = 1.f / (1.f + expf(-v));
    }
}

// ---------------- kernel 0b: fold Wo into output head ----------------------
__global__ __launch_bounds__(128) void k_fuse(const void* __restrict__ Wo,
                                              const void* __restrict__ outW,
                                              const void* __restrict__ bo,
                                              const void* __restrict__ outb,
                                              float* __restrict__ wfused,
                                              float* __restrict__ bfused,
                                              const int* __restrict__ flags) {
    int isbf = flags[0];
    int v = blockIdx.x; int h = threadIdx.x;
    __shared__ float ow[HH];
    __shared__ float red[HH];
    ow[h] = ldf(outW, (size_t)v * HH + h, isbf);
    __syncthreads();
    size_t wb = ((size_t)v * HH + h) * HH;
    float acc = 0.f;
    #pragma unroll 8
    for (int k = 0; k < HH; k++) acc += ldf(Wo, wb + k, isbf) * ow[k];
    wfused[v * HH + h] = acc;
    red[h] = ldf(bo, (size_t)v * HH + h, isbf) * ow[h];
    __syncthreads();
    for (int s = 64; s > 0; s >>= 1) { if (h < s) red[h] += red[h + s]; __syncthreads(); }
    if (h == 0) bfused[v] = red[0] + ldf(outb, v, isbf);
}

// ---------------- kernel 2: causal input -> zh/zl bf16 hi/lo ---------------
__global__ __launch_bounds__(256) void k_causal(const void* __restrict__ x,
                                                const float* __restrict__ adj,
                                                const void* __restrict__ var_emb,
                                                const void* __restrict__ temp_emb,
                                                u16* __restrict__ zh,
                                                u16* __restrict__ zl,
                                                const int* __restrict__ flags) {
    __shared__ float xl[LP1][VV];            // 2.75 KB
    __shared__ float A_sh[VV][VV + 1];       // 16.25 KB
    __shared__ float Blp_sh[VV * LP1 * 4];   // 11 KB partials
    __shared__ float Bl_sh[VV][12];          // 3 KB
    int isbf = flags[0];
    int tid = threadIdx.x;
    int bt = blockIdx.x; int b = bt >> 8; int t = bt & 255;

    for (int p = tid; p < LP1 * VV; p += 256) {
        int l = p >> 6, s = p & 63; int tt = t - l;
        xl[l][s] = (tt >= 0) ? ldf(x, (size_t)(b * SS + tt) * VV + s, isbf) : 0.f;
    }
    __syncthreads();

    // fused A + Bl-partial pass: thread has fixed i, 16 s values (s = sg + 4k)
    {
        int i = tid & 63, sg = tid >> 6;
        float blp[LP1];
        #pragma unroll
        for (int l = 0; l < LP1; l++) blp[l] = 0.f;
        for (int k = 0; k < 16; k++) {
            int s = sg + k * 4;
            const float* ap = adj + (s * VV + i) * LP1;
            float a = 0.f;
            #pragma unroll
            for (int l = 0; l < LP1; l++) {
                float pr = xl[l][s] * ap[l];
                a += pr; blp[l] += pr;
            }
            A_sh[i][s] = a;
        }
        #pragma unroll
        for (int l = 0; l < LP1; l++)
            Blp_sh[(i * LP1 + l) * 4 + sg] = blp[l];
    }
    __syncthreads();
    for (int p = tid; p < VV * LP1; p += 256) {
        int i = p / LP1, l = p - i * LP1;
        const float* q = &Blp_sh[(i * LP1 + l) * 4];
        Bl_sh[i][l] = (q[0] + q[1]) + (q[2] + q[3]);
    }
    __syncthreads();

    int h0 = (tid & 31) * 4;   // 4 h-values
    int ig = tid >> 5;         // 8 i-values
    float acc[8][4];
    #pragma unroll
    for (int ii = 0; ii < 8; ii++)
        #pragma unroll
        for (int j = 0; j < 4; j++) acc[ii][j] = 0.f;

    if (isbf) {
        for (int s = 0; s < VV; s++) {
            float4 v4 = ld4(var_emb, (size_t)s * HH + h0, 1);
            #pragma unroll
            for (int ii = 0; ii < 8; ii++) {
                float a = A_sh[ig * 8 + ii][s];
                acc[ii][0] += a * v4.x; acc[ii][1] += a * v4.y;
                acc[ii][2] += a * v4.z; acc[ii][3] += a * v4.w;
            }
        }
        #pragma unroll
        for (int l = 0; l < LP1; l++) {
            float4 t4 = ld4(temp_emb, (size_t)l * HH + h0, 1);
            #pragma unroll
            for (int ii = 0; ii < 8; ii++) {
                float bl = Bl_sh[ig * 8 + ii][l];
                acc[ii][0] += bl * t4.x; acc[ii][1] += bl * t4.y;
                acc[ii][2] += bl * t4.z; acc[ii][3] += bl * t4.w;
            }
        }
    } else {
        for (int s = 0; s < VV; s++) {
            float4 v4 = ld4(var_emb, (size_t)s * HH + h0, 0);
            #pragma unroll
            for (int ii = 0; ii < 8; ii++) {
                float a = A_sh[ig * 8 + ii][s];
                acc[ii][0] += a * v4.x; acc[ii][1] += a * v4.y;
                acc[ii][2] += a * v4.z; acc[ii][3] += a * v4.w;
            }
        }
        #pragma unroll
        for (int l = 0; l < LP1; l++) {
            float4 t4 = ld4(temp_emb, (size_t)l * HH + h0, 0);
            #pragma unroll
            for (int ii = 0; ii < 8; ii++) {
                float bl = Bl_sh[ig * 8 + ii][l];
                acc[ii][0] += bl * t4.x; acc[ii][1] += bl * t4.y;
                acc[ii][2] += bl * t4.z; acc[ii][3] += bl * t4.w;
            }
        }
    }

    #pragma unroll
    for (int ii = 0; ii < 8; ii++) {
        int i = ig * 8 + ii;
        size_t idx = ((size_t)i * BSZ + bt) * HH + h0;
        u16 h0_ = f2bf(acc[ii][0]), h1_ = f2bf(acc[ii][1]);
        u16 h2_ = f2bf(acc[ii][2]), h3_ = f2bf(acc[ii][3]);
        uint2 hw, lw;
        hw.x = (u32)h0_ | ((u32)h1_ << 16); hw.y = (u32)h2_ | ((u32)h3_ << 16);
        lw.x = (u32)f2bf(acc[ii][0] - bfbits2f(h0_)) | ((u32)f2bf(acc[ii][1] - bfbits2f(h1_)) << 16);
        lw.y = (u32)f2bf(acc[ii][2] - bfbits2f(h2_)) | ((u32)f2bf(acc[ii][3] - bfbits2f(h3_)) << 16);
        *(uint2*)&zh[idx] = hw;
        *(uint2*)&zl[idx] = lw;
    }
}

// ---------------- kernel Wp: weight pre-transpose, swizzled chunks ---------
// R16: output layout changed to chunk-contiguous pre-swizzled:
//   Whs[mat*16384 + c*8192 + n*64 + (kloc ^ ((n&7)*8))] = W^T[n][c*64+kloc]
// so k_mega can stage each 16 KB chunk with linear global_load_lds and read
// with a matching XOR (bank-conflict-free ds_read_b128).
struct WPack {
    const void* src[4];
    u16* dh[4];
    u16* dl[4];
};
#define TP 136   // u16 pitch
__global__ __launch_bounds__(256) void k_wprep(WPack wp,
                                               const int* __restrict__ flags) {
    int isbf = flags[0];
    int mat = blockIdx.x;
    int seg = (mat < 192) ? 0 : 1 + ((mat - 192) >> 6);
    int rel = (mat < 192) ? mat : ((mat - 192) & 63);
    const void* raw = wp.src[seg];
    u16* Wh = wp.dh[seg];
    u16* Wl = wp.dl[seg];
    int tid = threadIdx.x;
    size_t src = (size_t)rel * (HH * HH);
    if (isbf) {
        __shared__ u16 tile[HH * TP];   // 34 KB
        const uint4* sp = (const uint4*)((const u16*)raw + src);
        #pragma unroll
        for (int u = 0; u < 8; u++) {
            int p = u * 256 + tid;
            int h = p >> 4, k8 = (p & 15) * 8;
            int k8s = k8 ^ ((((u32)h >> 3) & 15) * 8);
            *(uint4*)&tile[h * TP + k8s] = sp[p];
        }
        __syncthreads();
        #pragma unroll
        for (int u = 0; u < 8; u++) {
            int p = u * 256 + tid;
            int kcol = p >> 4, h8 = (p & 15) * 8;   // kcol = n (out col), h8 = k base
            u16 vals[8];
            #pragma unroll
            for (int j = 0; j < 8; j++) {
                int h = h8 + j;
                int ks = kcol ^ ((((u32)h >> 3) & 15) * 8);
                vals[j] = tile[h * TP + ks];
            }
            uint4 pk;
            pk.x = (u32)vals[0] | ((u32)vals[1] << 16);
            pk.y = (u32)vals[2] | ((u32)vals[3] << 16);
            pk.z = (u32)vals[4] | ((u32)vals[5] << 16);
            pk.w = (u32)vals[6] | ((u32)vals[7] << 16);
            int c = h8 >> 6;
            int kloc = (h8 & 63) ^ ((kcol & 7) * 8);
            *(uint4*)&Wh[src + c * 8192 + kcol * 64 + kloc] = pk;
        }
    } else {
        int kcol = tid >> 1, h0 = (tid & 1) * 64;
        for (int i = 0; i < 64; i++) {
            int h = h0 + i;
            float w = ldf(raw, src + (size_t)h * HH + kcol, 0);
            u16 hi = f2bf(w);
            int c = h >> 6;
            size_t dst = src + c * 8192 + (size_t)kcol * 64 + ((h & 63) ^ ((kcol & 7) * 8));
            Wh[dst] = hi;
            Wl[dst] = f2bf(w - bfbits2f(hi));
        }
    }
}

// ---------------- kernel M: fused mech x3 + QKV, LDS-resident z ------------
// R16: all staging via global_load_lds (16B) into LINEAR swizzled LDS:
//   - z tile (hi/lo) staged once, per-lane source-swizzled.
//   - B chunks double-buffered; next chunk's gll issued BEFORE this chunk's
//     MFMA phase -> __syncthreads' vmcnt(0) drain finds them landed.
//   One barrier per chunk. No register prefetch (R15's spill disaster:
//   launch_bounds(256,3) forced 72 VGPR -> 400 MB scratch traffic).
// LDS: Az 2x16 KB + B 2x16 KB = 64 KB -> 2 blocks/CU, VGPR free (<=256).
#define PB  72   // u16 pitch for V-transpose scratch only
__global__ __launch_bounds__(256) void k_mega(
    const u16* __restrict__ zh, const u16* __restrict__ zl,
    const u16* __restrict__ WmH, const u16* __restrict__ WmL,
    const u16* __restrict__ WqH, const u16* __restrict__ WqL,
    const u16* __restrict__ WkH, const u16* __restrict__ WkL,
    const u16* __restrict__ WvH, const u16* __restrict__ WvL,
    const void* __restrict__ mechb,
    const void* __restrict__ lng, const void* __restrict__ lnb,
    const void* __restrict__ bq, const void* __restrict__ bk,
    const void* __restrict__ bv,
    u16* __restrict__ Qh, u16* __restrict__ Ql,
    u16* __restrict__ Ko, u16* __restrict__ Vt,
    const int* __restrict__ flags)
{
    __shared__ u16 Az_h[64 * 128];      // 16 KB, cols XOR-swizzled
    __shared__ u16 Az_l[64 * 128];      // 16 KB
    __shared__ u16 Bd_s[2][128 * 64];   // 32 KB dbuf, pre-swizzled image
    u16* Vt_sh = &Bd_s[0][0];           // V-transpose scratch (18.4 KB < 32 KB)
    int isbf = flags[0];
    int wexact = isbf;
    int tid = threadIdx.x;
    int bid = blockIdx.x;
    int xcd = bid & 7, idx = bid >> 3;
    int v = xcd * 8 + (idx >> 4);       // XCD-bijective: all 16 tiles of v together
    int tile = idx & 15;
    int wave = tid >> 6, lane = tid & 63;
    int quad = lane >> 4, l15 = lane & 15;
    int m0 = wave * 16;
    int swzl = (l15 & 7) * 8;           // XOR for A/B fragment reads

    size_t zbase = ((size_t)v * BSZ + (size_t)tile * 64) * HH;

    int shift = wexact ? 1 : 2;         // chunks per layer: 2 (hi) or 4 (hi+lo)
    int PER = 1 << shift;
    int NCH = 6 << shift;

    auto wchunk = [&](int ch) -> const u16* {
        int li = ch >> shift;
        int sub = ch & (PER - 1);
        int cc = sub & 1, lo = sub >> 1;
        const u16* p; size_t wb;
        if (li < 3)       { p = lo ? WmL : WmH; wb = (size_t)(v * NLL + li) * 16384; }
        else if (li == 3) { p = lo ? WqL : WqH; wb = (size_t)v * 16384; }
        else if (li == 4) { p = lo ? WkL : WkH; wb = (size_t)v * 16384; }
        else              { p = lo ? WvL : WvH; wb = (size_t)v * 16384; }
        return p + wb + cc * 8192;
    };
    // stage one 16 KB pre-swizzled chunk: 4 gll/wave, fully linear
    auto stageB = [&](u16* dst, const u16* g) {
        const u16* gl = g + wave * 2048 + lane * 8;
        u16* lb = dst + wave * 2048;
        #pragma unroll
        for (int u = 0; u < 4; u++)
            gll16(gl + u * 512, lb + u * 512);
    };

    // ---- prologue: stage z (hi+lo, source-swizzled) + B chunk 0 ----
    {
        int rl = lane >> 4;             // 0..3
        int kc = (lane & 15) * 8;       // 0..120
        #pragma unroll
        for (int u = 0; u < 4; u++) {
            int row = wave * 16 + u * 4 + rl;
            int kcs = kc ^ ((row & 7) * 8);
            gll16(&zh[zbase + (size_t)row * HH + kcs], &Az_h[(wave * 16 + u * 4) * 128]);
            gll16(&zl[zbase + (size_t)row * HH + kcs], &Az_l[(wave * 16 + u * 4) * 128]);
        }
    }
    stageB(&Bd_s[0][0], wchunk(0));
    __syncthreads();

    f32x4 acc[8];

    auto epilogue = [&](int li) {
        float bcol[8], gcol[8], b2col[8];
        #pragma unroll
        for (int nt = 0; nt < 8; nt++) {
            int col = nt * 16 + l15;
            if (li < 3) {
                size_t pb = (size_t)v * (NLL * HH) + (size_t)li * HH + col;
                bcol[nt]  = ldf(mechb, pb, isbf);
                gcol[nt]  = ldf(lng, pb, isbf);
                b2col[nt] = ldf(lnb, pb, isbf);
            } else {
                const void* bp = (li == 3) ? bq : (li == 4) ? bk : bv;
                bcol[nt] = ldf(bp, (size_t)v * HH + col, isbf);
            }
        }
        if (li == 5) __syncthreads();   // claim Bd_s as V-transpose scratch
        #pragma unroll
        for (int r = 0; r < 4; r++) {
            float vals[8];
            float sum = 0.f, sq = 0.f;
            #pragma unroll
            for (int nt = 0; nt < 8; nt++) {
                float val = acc[nt][r] + bcol[nt];
                vals[nt] = val; sum += val; sq += val * val;
            }
            int rloc = m0 + quad * 4 + r;
            if (li < 3) {
                #pragma unroll
                for (int m = 1; m < 16; m <<= 1) {
                    sum += __shfl_xor(sum, m);
                    sq  += __shfl_xor(sq, m);
                }
                float mean = sum * (1.f / HH);
                float var  = sq * (1.f / HH) - mean * mean;
                float rstd = rsqrtf(var + 1e-5f);
                int swr = (rloc & 7) * 8;
                #pragma unroll
                for (int nt = 0; nt < 8; nt++) {
                    float y = (vals[nt] - mean) * rstd * gcol[nt] + b2col[nt];
                    y = 0.5f * y * (1.f + erff(y * 0.70710678118654752f));
                    u16 hi = f2bf(y);
                    int colw = (nt * 16 + l15) ^ swr;
                    Az_h[rloc * 128 + colw] = hi;
                    Az_l[rloc * 128 + colw] = f2bf(y - bfbits2f(hi));
                }
            } else if (li == 3) {       // Q hi/lo
                int row = tile * 64 + rloc;
                size_t ob = ((size_t)v * BSZ + row) * HH;
                #pragma unroll
                for (int nt = 0; nt < 8; nt++) {
                    u16 hi = f2bf(vals[nt]);
                    Qh[ob + nt * 16 + l15] = hi;
                    Ql[ob + nt * 16 + l15] = f2bf(vals[nt] - bfbits2f(hi));
                }
            } else if (li == 4) {       // K natural bf16
                int row = tile * 64 + rloc;
                size_t ob = ((size_t)v * BSZ + row) * HH;
                #pragma unroll
                for (int nt = 0; nt < 8; nt++)
                    Ko[ob + nt * 16 + l15] = f2bf(vals[nt]);
            } else {                    // V: stage transposed tile in LDS
                #pragma unroll
                for (int nt = 0; nt < 8; nt++)
                    Vt_sh[(nt * 16 + l15) * PB + rloc] = f2bf(vals[nt]);
            }
        }
        if (li == 5) {
            __syncthreads();
            // coalesced V store: 128 (head,d) rows x 64 tt, full 64B lines
            int col = tid >> 1, half = tid & 1;
            int n = col >> 4, d = col & 15;
            int bb = tile >> 2, t0 = (tile & 3) * 64;
            size_t dst = (((size_t)(v * BB + bb) * NHH + n) * DHH + d) * SS + t0 + half * 32;
            #pragma unroll
            for (int j = 0; j < 4; j++)
                *(uint4*)&Vt[dst + j * 8] = *(const uint4*)&Vt_sh[col * PB + half * 32 + j * 8];
        }
    };

    for (int ch = 0; ch < NCH; ch++) {
        int bsel = ch & 1;
        if (ch + 1 < NCH) stageB(&Bd_s[bsel ^ 1][0], wchunk(ch + 1));
        int sub = ch & (PER - 1);
        int li = ch >> shift;
        int cc = sub & 1, lo = sub >> 1;
        if (sub == 0) {
            #pragma unroll
            for (int nt = 0; nt < 8; nt++) {
                f32x4 zz = {0.f, 0.f, 0.f, 0.f};
                acc[nt] = zz;
            }
        }
        const u16* Bp = &Bd_s[bsel][0];
        #pragma unroll
        for (int kk = 0; kk < 2; kk++) {
            int acol = (cc * 64 + kk * 32 + quad * 8) ^ swzl;
            int bcol = (kk * 32 + quad * 8) ^ swzl;
            s16x8 ah = *(const s16x8*)&Az_h[(m0 + l15) * 128 + acol];
            if (!lo) {
                s16x8 al = *(const s16x8*)&Az_l[(m0 + l15) * 128 + acol];
                #pragma unroll
                for (int nt = 0; nt < 8; nt++) {
                    s16x8 bh = *(const s16x8*)&Bp[(nt * 16 + l15) * 64 + bcol];
                    acc[nt] = __builtin_amdgcn_mfma_f32_16x16x32_bf16(ah, bh, acc[nt], 0, 0, 0);
                    acc[nt] = __builtin_amdgcn_mfma_f32_16x16x32_bf16(al, bh, acc[nt], 0, 0, 0);
                }
            } else {
                #pragma unroll
                for (int nt = 0; nt < 8; nt++) {
                    s16x8 bl = *(const s16x8*)&Bp[(nt * 16 + l15) * 64 + bcol];
                    acc[nt] = __builtin_amdgcn_mfma_f32_16x16x32_bf16(ah, bl, acc[nt], 0, 0, 0);
                }
            }
        }
        if (sub == PER - 1) epilogue(li);
        __syncthreads();
    }
}

// ---------------- kernel 5: MFMA attention, 4 waves / (v,b,head) -----------
#define LDW 40
__global__ __launch_bounds__(256) void k_attn2(const u16* __restrict__ Qh,
                                               const u16* __restrict__ Ql,
                                               const u16* __restrict__ K16,
                                               const u16* __restrict__ Vt,
                                               float* __restrict__ O) {
    __shared__ u16 Kp_sh[SS * LDW];        // 20 KB: cols 0-15 = K, 16-31 = K dup
    __shared__ u16 Vt_sh[DHH * 264];       // 8.25 KB
    __shared__ u16 P_sh[4][16 * LDW];      // per-wave P tile
    int tid = threadIdx.x;
    int wave = tid >> 6, lane = tid & 63;
    int quad = lane >> 4, l15 = lane & 15;
    int bn = blockIdx.x, v = blockIdx.y;
    int b = bn >> 3, n = bn & 7;
    size_t qkbase = ((size_t)v * BSZ + b * SS) * HH + n * DHH;
    size_t vtbase = ((size_t)(v * BB + b) * NHH + n) * DHH * SS;

    {
        int row = tid;
        uint4 k0 = *(const uint4*)&K16[qkbase + (size_t)row * HH];
        uint4 k1 = *(const uint4*)&K16[qkbase + (size_t)row * HH + 8];
        *(uint4*)&Kp_sh[row * LDW + 0]  = k0;
        *(uint4*)&Kp_sh[row * LDW + 8]  = k1;
        *(uint4*)&Kp_sh[row * LDW + 16] = k0;
        *(uint4*)&Kp_sh[row * LDW + 24] = k1;
    }
    #pragma unroll
    for (int u = 0; u < 2; u++) {
        int p = u * 256 + tid;
        int d = p >> 5, su = (p & 31) * 8;
        *(uint4*)&Vt_sh[d * 264 + su] = *(const uint4*)&Vt[vtbase + (size_t)d * SS + su];
    }
    __syncthreads();

    s16x8 ones;
    #pragma unroll
    for (int i = 0; i < 8; i++) ones[i] = (short)0x3F80;

    for (int mt = wave * 4; mt < wave * 4 + 4; mt++) {
        const u16* Qsrc = (quad < 2) ? Qh : Ql;
        s16x8 aq = *(const s16x8*)&Qsrc[qkbase + (size_t)(mt * 16 + l15) * HH + (quad & 1) * 8];
        f32x4 oacc = {0.f, 0.f, 0.f, 0.f};
        f32x4 lacc = {0.f, 0.f, 0.f, 0.f};
        for (int jt2 = 0; jt2 < 8; jt2++) {
            #pragma unroll
            for (int sub = 0; sub < 2; sub++) {
                int jt = jt2 * 2 + sub;
                s16x8 bk = *(const s16x8*)&Kp_sh[(jt * 16 + l15) * LDW + quad * 8];
                f32x4 s = {0.f, 0.f, 0.f, 0.f};
                s = __builtin_amdgcn_mfma_f32_16x16x32_bf16(aq, bk, s, 0, 0, 0);
                #pragma unroll
                for (int r = 0; r < 4; r++) {
                    float p = __expf(s[r] * 0.25f);
                    P_sh[wave][(quad * 4 + r) * LDW + sub * 16 + l15] = f2bf_trunc(p);
                }
            }
            s16x8 ap = *(const s16x8*)&P_sh[wave][l15 * LDW + quad * 8];
            s16x8 bv = *(const s16x8*)&Vt_sh[l15 * 264 + jt2 * 32 + quad * 8];
            oacc = __builtin_amdgcn_mfma_f32_16x16x32_bf16(ap, bv, oacc, 0, 0, 0);
            lacc = __builtin_amdgcn_mfma_f32_16x16x32_bf16(ap, ones, lacc, 0, 0, 0);
        }
        #pragma unroll
        for (int r = 0; r < 4; r++) {
            float val = oacc[r] / lacc[r];
            O[((size_t)v * BSZ + b * SS + mt * 16 + quad * 4 + r) * HH + n * DHH + l15] = val;
        }
    }
}

// ---------------- kernel 6: fused output head (coalesced) ------------------
__global__ __launch_bounds__(256) void k_final(const float* __restrict__ o,
                                               const float* __restrict__ wfused,
                                               const float* __restrict__ bfused,
                                               void* __restrict__ out,
                                               const int* __restrict__ flags) {
    __shared__ float wf[HH];
    int isbf = flags[0];
    int tid = threadIdx.x; int b = blockIdx.x; int v = blockIdx.y;
    if (tid < HH) wf[tid] = wfused[v * HH + tid];
    __syncthreads();
    int rg = tid >> 3;
    int l8 = tid & 7;
    float4 w0 = *(const float4*)&wf[l8 * 16];
    float4 w1 = *(const float4*)&wf[l8 * 16 + 4];
    float4 w2 = *(const float4*)&wf[l8 * 16 + 8];
    float4 w3 = *(const float4*)&wf[l8 * 16 + 12];
    float bv = bfused[v];
    #pragma unroll
    for (int pass = 0; pass < 8; pass++) {
        int bt = b * SS + pass * 32 + rg;
        const float4* orow = (const float4*)(o + ((size_t)v * BSZ + bt) * HH + l8 * 16);
        float4 a0 = orow[0], a1 = orow[1], a2 = orow[2], a3 = orow[3];
        float acc = a0.x * w0.x + a0.y * w0.y + a0.z * w0.z + a0.w * w0.w
                  + a1.x * w1.x + a1.y * w1.y + a1.z * w1.z + a1.w * w1.w
                  + a2.x * w2.x + a2.y * w2.y + a2.z * w2.z + a2.w * w2.w
                  + a3.x * w3.x + a3.y * w3.y + a3.z * w3.z + a3.w * w3.w;
        acc += __shfl_xor(acc, 1);
        acc += __shfl_xor(acc, 2);
        acc += __shfl_xor(acc, 4);
        if (l8 == 0) {
            float pred = acc + bv;
            size_t oi = (size_t)bt * VV + v;
            if (isbf) ((u16*)out)[oi] = f2bf(pred);
            else      ((float*)out)[oi] = pred;
        }
    }
}

extern "C" void kernel_launch(void* const* d_in, const int* in_sizes, int n_in,
                              void* d_out, int out_size, void* d_ws, size_t ws_size,
                              hipStream_t stream) {
    (void)out_size; (void)ws_size;

    // ---- resolve input permutation from in_sizes (host-side, capture-safe) ----
    static const int dict_sizes[18]  = {65536,45056,8192,1408,3145728,24576,24576,24576,
                                        1048576,1048576,1048576,1048576,8192,8192,8192,8192,8192,64};
    static const int alpha_sizes[18] = {1048576,1048576,1048576,1048576,45056,8192,8192,8192,
                                        8192,24576,24576,3145728,24576,8192,64,1408,8192,65536};
    static const int alpha_pos[18]   = {17,4,16,15,11,12,10,9,2,0,3,1,7,5,8,6,13,14};
    static const int alpha_logical[18] = {9,11,8,10,1,13,15,12,14,7,6,4,5,16,17,3,2,0};

    const void* in[18];
    bool is_dict = (n_in == 18), is_alpha = (n_in == 18);
    for (int i = 0; i < 18 && i < n_in; i++) {
        if (in_sizes[i] != dict_sizes[i])  is_dict = false;
        if (in_sizes[i] != alpha_sizes[i]) is_alpha = false;
    }
    if (is_dict) {
        for (int i = 0; i < 18; i++) in[i] = d_in[i];
    } else if (is_alpha) {
        for (int i = 0; i < 18; i++) in[i] = d_in[alpha_pos[i]];
    } else {
        bool used[18] = {false};
        for (int a = 0; a < 18; a++) {
            int lg = alpha_logical[a];
            for (int i = 0; i < n_in && i < 18; i++) {
                if (!used[i] && in_sizes[i] == dict_sizes[lg]) {
                    in[lg] = d_in[i]; used[i] = true; break;
                }
            }
        }
    }

    const void* x        = in[0];
    const void* adjl     = in[1];
    const void* var_emb  = in[2];
    const void* temp_emb = in[3];
    const void* mechW    = in[4];
    const void* mechb    = in[5];
    const void* lng      = in[6];
    const void* lnb      = in[7];
    const void* Wq       = in[8];
    const void* Wk       = in[9];
    const void* Wv       = in[10];
    const void* Wo       = in[11];
    const void* bq       = in[12];
    const void* bk       = in[13];
    const void* bv       = in[14];
    const void* bo       = in[15];
    const void* outW     = in[16];
    const void* outb     = in[17];

    // workspace (f32-unit offsets), total 126.0 MB
    float* ws     = (float*)d_ws;
    int*   flags  = (int*)ws;                   // 32 f
    float* adj    = ws + 32;                    // 45056
    float* wfused = ws + 45088;                 // 8192
    float* bfused = ws + 53280;                 // 64 (to 53376)
    u16*   zhA    = (u16*)(ws + 53376);         // -> 4247680  (causal z hi)
    u16*   zlA    = (u16*)(ws + 4247680);       // -> 8441984  (causal z lo)
    u16*   zhB    = (u16*)(ws + 8441984);       // -> 12636288 (Q hi)
    u16*   zlB    = (u16*)(ws + 12636288);      // -> 16830592 (Q lo)
    float* Obuf   = ws + 53376;                 // overlays zhA+zlA (dead by attn)
    u16*   K16    = (u16*)(ws + 16830592);      // -> 21024896
    u16*   Vt16   = (u16*)(ws + 21024896);      // -> 25219200
    u16*   WtmH   = (u16*)(ws + 25219200);      // -> 26792064
    u16*   WtmL   = (u16*)(ws + 26792064);      // -> 28364928
    u16*   WtqH   = (u16*)(ws + 28364928);      // -> 28889216
    u16*   WtqL   = (u16*)(ws + 28889216);      // -> 29413504
    u16*   WtkH   = (u16*)(ws + 29413504);      // -> 29937792
    u16*   WtkL   = (u16*)(ws + 29937792);      // -> 30462080
    u16*   WtvH   = (u16*)(ws + 30462080);      // -> 30986368
    u16*   WtvL   = (u16*)(ws + 30986368);      // -> 31510656

    k_sniff <<<dim3(1),    dim3(64),  0, stream>>>((const u16*)mechW, flags);
    k_adj   <<<dim3(176),  dim3(256), 0, stream>>>(adjl, adj, flags);
    k_fuse  <<<dim3(64),   dim3(128), 0, stream>>>(Wo, outW, bo, outb, wfused, bfused, flags);

    // k_wprep moved BEFORE k_causal: tests whether its ~100 us window was the
    // drain shadow of k_causal's 67 MB of stores (R14 control observation).
    WPack wp;
    wp.src[0] = mechW; wp.dh[0] = WtmH; wp.dl[0] = WtmL;
    wp.src[1] = Wq;    wp.dh[1] = WtqH; wp.dl[1] = WtqL;
    wp.src[2] = Wk;    wp.dh[2] = WtkH; wp.dl[2] = WtkL;
    wp.src[3] = Wv;    wp.dh[3] = WtvH; wp.dl[3] = WtvL;
    k_wprep <<<dim3(384),  dim3(256), 0, stream>>>(wp, flags);

    k_causal<<<dim3(BSZ),  dim3(256), 0, stream>>>(x, adj, var_emb, temp_emb, zhA, zlA, flags);

    // fused mech x3 + QKV: z resident in LDS, gll-staged, dbuf-pipelined
    k_mega<<<dim3(1024), dim3(256), 0, stream>>>(
            zhA, zlA,
            WtmH, WtmL, WtqH, WtqL, WtkH, WtkL, WtvH, WtvL,
            mechb, lng, lnb, bq, bk, bv,
            zhB, zlB, K16, Vt16, flags);

    k_attn2 <<<dim3(BB * NHH, VV), dim3(256), 0, stream>>>(zhB, zlB, K16, Vt16, Obuf);
    k_final <<<dim3(BB, VV), dim3(256), 0, stream>>>(Obuf, wfused, bfused, d_out, flags);
}

// Round 4
// 402.998 us; speedup vs baseline: 1.1964x; 1.0435x over previous
//
#include <hip/hip_runtime.h>
#include <math.h>

// Problem constants
#define BB   4
#define SS   256
#define VV   64
#define LP1  11
#define HH   128
#define NHH  8
#define DHH  16
#define NLL  3
#define BSZ  1024   // BB*SS

typedef unsigned short u16;
typedef unsigned int   u32;
typedef __attribute__((ext_vector_type(8))) short s16x8;   // 8 bf16 (4 VGPR)
typedef __attribute__((ext_vector_type(4))) float f32x4;   // MFMA acc

__device__ __forceinline__ float bfbits2f(u32 hi16) {
    u32 i = hi16 << 16; float f; __builtin_memcpy(&f, &i, 4); return f;
}
__device__ __forceinline__ u16 f2bf(float f) {
    u32 i; __builtin_memcpy(&i, &f, 4);
    return (u16)((i + 0x7fffu + ((i >> 16) & 1u)) >> 16);
}
__device__ __forceinline__ u16 f2bf_trunc(float f) {
    u32 i; __builtin_memcpy(&i, &f, 4);
    return (u16)(i >> 16);
}
// packed f32x2 -> bf16x2 (RNE). lo 16 bits = first operand.
__device__ __forceinline__ u32 cvtpk(float lo, float hi) {
    u32 r;
    asm("v_cvt_pk_bf16_f32 %0, %1, %2" : "=v"(r) : "v"(lo), "v"(hi));
    return r;
}
__device__ __forceinline__ float ldf(const void* p, size_t i, int isbf) {
    if (isbf) return bfbits2f(((const u16*)p)[i]);
    return ((const float*)p)[i];
}
__device__ __forceinline__ float4 ld4(const void* p, size_t i, int isbf) {
    float4 v;
    if (isbf) {
        uint2 u = *(const uint2*)((const u16*)p + i);
        v.x = bfbits2f(u.x & 0xffffu); v.y = bfbits2f(u.x >> 16);
        v.z = bfbits2f(u.y & 0xffffu); v.w = bfbits2f(u.y >> 16);
    } else {
        v = *(const float4*)((const float*)p + i);
    }
    return v;
}
// async global->LDS, 16B per lane. LDS dest = wave-uniform base + lane*16.
__device__ __forceinline__ void gll16(const u16* g, u16* l) {
    __builtin_amdgcn_global_load_lds(
        (const __attribute__((address_space(1))) void*)g,
        (__attribute__((address_space(3))) void*)l, 16, 0, 0);
}

// ---------- kernel S: global dtype sniff on mech_W (random, nonzero) -------
__global__ __launch_bounds__(64) void k_sniff(const u16* __restrict__ probe,
                                              int* __restrict__ flags) {
    if (threadIdx.x == 0) {
        int wild = 0;
        for (int j = 0; j < 256; j++) {
            float v = bfbits2f(probe[j]);
            if (!(fabsf(v) < 1e8f)) wild = 1;
        }
        flags[0] = wild ? 0 : 1;   // 1 = bf16 storage (inputs exact; bf16 output)
    }
}

// ---------------- kernel 1: adj = sigmoid(adjacency_logits) ----------------
__global__ __launch_bounds__(256) void k_adj(const void* __restrict__ logits,
                                             float* __restrict__ adj,
                                             const int* __restrict__ flags) {
    int isbf = flags[0];
    int i = blockIdx.x * 256 + threadIdx.x;
    if (i < VV * VV * LP1) {
        float v = ldf(logits, i, isbf);
        adj[i] = 1.f / (1.f + expf(-v));
    }
}

// ---------------- kernel 0b: fold Wo into output head ----------------------
__global__ __launch_bounds__(128) void k_fuse(const void* __restrict__ Wo,
                                              const void* __restrict__ outW,
                                              const void* __restrict__ bo,
                                              const void* __restrict__ outb,
                                              float* __restrict__ wfused,
                                              float* __restrict__ bfused,
                                              const int* __restrict__ flags) {
    int isbf = flags[0];
    int v = blockIdx.x; int h = threadIdx.x;
    __shared__ float ow[HH];
    __shared__ float red[HH];
    ow[h] = ldf(outW, (size_t)v * HH + h, isbf);
    __syncthreads();
    size_t wb = ((size_t)v * HH + h) * HH;
    float acc = 0.f;
    #pragma unroll 8
    for (int k = 0; k < HH; k++) acc += ldf(Wo, wb + k, isbf) * ow[k];
    wfused[v * HH + h] = acc;
    red[h] = ldf(bo, (size_t)v * HH + h, isbf) * ow[h];
    __syncthreads();
    for (int s = 64; s > 0; s >>= 1) { if (h < s) red[h] += red[h + s]; __syncthreads(); }
    if (h == 0) bfused[v] = red[0] + ldf(outb, v, isbf);
}

// ---------------- kernel Wp: weight pre-transpose, swizzled chunks ---------
// Chunk-contiguous pre-swizzled output (R16 format):
//   Whs[mat*16384 + c*8192 + n*64 + (kloc ^ ((n&7)*8))] = W^T[n][c*64+kloc]
// R17: +2 blocks (384: var_emb^T, 385: temp_emb^T padded to k=64) in the
// same chunk format, so k_mega can MFMA the causal z-formation directly.
struct WPack {
    const void* src[6];
    u16* dh[6];
    u16* dl[6];
};
#define TP 136   // u16 pitch
__global__ __launch_bounds__(256) void k_wprep(WPack wp,
                                               const int* __restrict__ flags) {
    int isbf = flags[0];
    int mat = blockIdx.x;
    int tid = threadIdx.x;
    if (mat >= 384) {
        if (mat == 384) {   // var_emb: [64 s][128 h] -> chunk [n=h][k=s]
            const void* raw = wp.src[4];
            u16* dh = wp.dh[4]; u16* dl = wp.dl[4];
            int n = tid >> 1, half = tid & 1;
            for (int i = 0; i < 32; i++) {
                int s = half * 32 + i;
                float val = ldf(raw, (size_t)s * HH + n, isbf);
                u16 hi = f2bf(val);
                int dst = n * 64 + (s ^ ((n & 7) * 8));
                dh[dst] = hi;
                dl[dst] = f2bf(val - bfbits2f(hi));
            }
        } else {            // temp_emb: [11 l][128 h] -> chunk [n=h][k=l pad 64]
            const void* raw = wp.src[5];
            u16* dh = wp.dh[5]; u16* dl = wp.dl[5];
            for (int p = tid; p < 8192; p += 256) { dh[p] = 0; dl[p] = 0; }
            __syncthreads();
            if (tid < HH) {
                int n = tid;
                for (int l = 0; l < LP1; l++) {
                    float val = ldf(raw, (size_t)l * HH + n, isbf);
                    u16 hi = f2bf(val);
                    int dst = n * 64 + (l ^ ((n & 7) * 8));
                    dh[dst] = hi;
                    dl[dst] = f2bf(val - bfbits2f(hi));
                }
            }
        }
        return;
    }
    int seg = (mat < 192) ? 0 : 1 + ((mat - 192) >> 6);
    int rel = (mat < 192) ? mat : ((mat - 192) & 63);
    const void* raw = wp.src[seg];
    u16* Wh = wp.dh[seg];
    u16* Wl = wp.dl[seg];
    size_t src = (size_t)rel * (HH * HH);
    if (isbf) {
        __shared__ u16 tile[HH * TP];   // 34 KB
        const uint4* sp = (const uint4*)((const u16*)raw + src);
        #pragma unroll
        for (int u = 0; u < 8; u++) {
            int p = u * 256 + tid;
            int h = p >> 4, k8 = (p & 15) * 8;
            int k8s = k8 ^ ((((u32)h >> 3) & 15) * 8);
            *(uint4*)&tile[h * TP + k8s] = sp[p];
        }
        __syncthreads();
        #pragma unroll
        for (int u = 0; u < 8; u++) {
            int p = u * 256 + tid;
            int kcol = p >> 4, h8 = (p & 15) * 8;   // kcol = n (out col), h8 = k base
            u16 vals[8];
            #pragma unroll
            for (int j = 0; j < 8; j++) {
                int h = h8 + j;
                int ks = kcol ^ ((((u32)h >> 3) & 15) * 8);
                vals[j] = tile[h * TP + ks];
            }
            uint4 pk;
            pk.x = (u32)vals[0] | ((u32)vals[1] << 16);
            pk.y = (u32)vals[2] | ((u32)vals[3] << 16);
            pk.z = (u32)vals[4] | ((u32)vals[5] << 16);
            pk.w = (u32)vals[6] | ((u32)vals[7] << 16);
            int c = h8 >> 6;
            int kloc = (h8 & 63) ^ ((kcol & 7) * 8);
            *(uint4*)&Wh[src + c * 8192 + kcol * 64 + kloc] = pk;
        }
    } else {
        int kcol = tid >> 1, h0 = (tid & 1) * 64;
        for (int i = 0; i < 64; i++) {
            int h = h0 + i;
            float w = ldf(raw, src + (size_t)h * HH + kcol, 0);
            u16 hi = f2bf(w);
            int c = h >> 6;
            size_t dst = src + c * 8192 + (size_t)kcol * 64 + ((h & 63) ^ ((kcol & 7) * 8));
            Wh[dst] = hi;
            Wl[dst] = f2bf(w - bfbits2f(hi));
        }
    }
}

// ---------------- kernel M: FULLY fused causal + mech x3 + QKV -------------
// R17: k_causal is folded in. Per block (v, 64-row bt tile):
//   P0: stage X window (74x64 fp32, transposed [s][t]) into Az-region LDS
//   P1: A[t][s], Bl[t][l] on VALU (wave-uniform s -> broadcast reads)
//   P2: A/Bl -> bf16 hi/lo MFMA fragments in registers
//   P3: stage ve^T/te^T chunks, z = A.ve + Bl.te via MFMA -> acc
//   P4: z epilogue (hi/lo split via cvt_pk, paired u32 LDS stores) -> Az
//   P5: 12-chunk mech/QKV main loop (unchanged from R3) + cvt_pk epilogues
// Removes 67 MB z write + 33.6 MB z fetch + the k_causal dispatch.
// LDS: one 64 KB block (Az 32 KB overlaid with X, Bd 32 KB overlaid with
// A/Bl scratch and V-transpose buffer) -> 2 blocks/CU.
#define PB  72   // u16 pitch for V-transpose scratch only
__global__ __launch_bounds__(256) void k_mega(
    const void* __restrict__ x, const float* __restrict__ adjp,
    const u16* __restrict__ VeH, const u16* __restrict__ VeL,
    const u16* __restrict__ TeH, const u16* __restrict__ TeL,
    const u16* __restrict__ WmH, const u16* __restrict__ WmL,
    const u16* __restrict__ WqH, const u16* __restrict__ WqL,
    const u16* __restrict__ WkH, const u16* __restrict__ WkL,
    const u16* __restrict__ WvH, const u16* __restrict__ WvL,
    const void* __restrict__ mechb,
    const void* __restrict__ lng, const void* __restrict__ lnb,
    const void* __restrict__ bq, const void* __restrict__ bk,
    const void* __restrict__ bv,
    u16* __restrict__ Qh, u16* __restrict__ Ql,
    u16* __restrict__ Ko, u16* __restrict__ Vt,
    const int* __restrict__ flags)
{
    __shared__ __align__(16) u16 SMEM[32768];   // 64 KB
    u16* Az_h = SMEM;                  // [64][128] swizzled
    u16* Az_l = SMEM + 8192;
    u16* BdS  = SMEM + 16384;          // double buffer: +bsel*8192
    u16* Vt_sh = BdS;                  // V-transpose scratch (18.4 KB)

    int isbf = flags[0];
    int wexact = isbf;
    int tid = threadIdx.x;
    int bid = blockIdx.x;
    int xcd = bid & 7, idx = bid >> 3;
    int v = xcd * 8 + (idx >> 4);      // XCD-bijective: 16 tiles of v together
    int tile = idx & 15;
    int b = tile >> 2, t0 = (tile & 3) * 64;
    int wave = tid >> 6, lane = tid & 63;
    int quad = lane >> 4, l15 = lane & 15;
    int m0 = wave * 16;
    int swzl = (l15 & 7) * 8;          // XOR for A/B fragment reads

    // ---- P0: stage X window transposed: xt[s][rr], rr = trow-(t0-10) ----
    float* xt = (float*)SMEM;          // [64 s][81] = 20.7 KB (Az region)
    for (int p = tid; p < 74 * 64; p += 256) {
        int rr = p >> 6, s = p & 63;
        int trow = t0 - 10 + rr;
        float val = (trow >= 0) ? ldf(x, (size_t)(b * SS + trow) * VV + s, isbf) : 0.f;
        xt[s * 81 + rr] = val;
    }
    __syncthreads();

    // ---- P1: A[t][s], Bl partials (Bd region scratch) ----
    float* A_f = (float*)BdS;          // [64][68] = 17.4 KB
    float* Blp = A_f + 64 * 68;        // [64][4][11] = 11.3 KB
    float* Blf = Blp + 64 * 44;        // [64][16] = 4 KB (total 32.7... = 32768 B)
    {
        int t = lane;                  // t = tid&63
        int sg = wave;                 // wave-uniform s range
        float blp[LP1];
        #pragma unroll
        for (int l = 0; l < LP1; l++) blp[l] = 0.f;
        for (int k = 0; k < 16; k++) {
            int s = sg * 16 + k;
            const float* ap = adjp + (s * VV + v) * LP1;
            float xw[LP1];
            #pragma unroll
            for (int j = 0; j < LP1; j++) xw[j] = xt[s * 81 + t + j];
            float a = 0.f;
            #pragma unroll
            for (int l = 0; l < LP1; l++) {
                float pr = xw[10 - l] * ap[l];
                a += pr; blp[l] += pr;
            }
            A_f[t * 68 + s] = a;
        }
        #pragma unroll
        for (int l = 0; l < LP1; l++) Blp[t * 44 + sg * 11 + l] = blp[l];
    }
    __syncthreads();
    {
        int t = tid >> 2, c0 = (tid & 3) * 4;
        #pragma unroll
        for (int c = c0; c < c0 + 4; c++) {
            float s4 = 0.f;
            if (c < LP1)
                s4 = (Blp[t * 44 + c] + Blp[t * 44 + 11 + c]) +
                     (Blp[t * 44 + 22 + c] + Blp[t * 44 + 33 + c]);
            Blf[t * 16 + c] = s4;
        }
    }
    __syncthreads();

    // ---- P2: A/Bl fragments -> regs (hi/lo bf16) ----
    s16x8 ahf[2], alf[2], blh, bll;
    #pragma unroll
    for (int kk = 0; kk < 2; kk++) {
        #pragma unroll
        for (int j = 0; j < 8; j++) {
            float a = A_f[(m0 + l15) * 68 + kk * 32 + quad * 8 + j];
            u32 w = cvtpk(a, a);
            u16 hi = (u16)(w & 0xffffu);
            ahf[kk][j] = (short)hi;
            float res = a - bfbits2f(hi);
            alf[kk][j] = (short)(cvtpk(res, res) & 0xffffu);
        }
    }
    #pragma unroll
    for (int j = 0; j < 8; j++) {
        float a = (quad < 2) ? Blf[(m0 + l15) * 16 + quad * 8 + j] : 0.f;
        u32 w = cvtpk(a, a);
        u16 hi = (u16)(w & 0xffffu);
        blh[j] = (short)hi;
        float res = a - bfbits2f(hi);
        bll[j] = (short)(cvtpk(res, res) & 0xffffu);
    }
    __syncthreads();                   // Bd scratch consumed

    // stage one 16 KB (8192 u16) pre-swizzled chunk: 4 gll/wave, linear
    auto stageB = [&](u16* dst, const u16* g) {
        const u16* gl = g + wave * 2048 + lane * 8;
        u16* lb = dst + wave * 2048;
        #pragma unroll
        for (int u = 0; u < 4; u++)
            gll16(gl + u * 512, lb + u * 512);
    };

    f32x4 acc[8];
    #pragma unroll
    for (int nt = 0; nt < 8; nt++) {
        f32x4 zz = {0.f, 0.f, 0.f, 0.f};
        acc[nt] = zz;
    }

    // ---- P3: z = A.ve + Bl.te via MFMA ----
    if (wexact) {
        stageB(BdS, VeH);
        stageB(BdS + 8192, TeH);
        __syncthreads();
        #pragma unroll
        for (int kk = 0; kk < 2; kk++) {
            int bcol = (kk * 32 + quad * 8) ^ swzl;
            #pragma unroll
            for (int nt = 0; nt < 8; nt++) {
                s16x8 bh = *(const s16x8*)&BdS[(nt * 16 + l15) * 64 + bcol];
                acc[nt] = __builtin_amdgcn_mfma_f32_16x16x32_bf16(ahf[kk], bh, acc[nt], 0, 0, 0);
                acc[nt] = __builtin_amdgcn_mfma_f32_16x16x32_bf16(alf[kk], bh, acc[nt], 0, 0, 0);
            }
        }
        {
            int bcol = (quad * 8) ^ swzl;
            #pragma unroll
            for (int nt = 0; nt < 8; nt++) {
                s16x8 th = *(const s16x8*)&BdS[8192 + (nt * 16 + l15) * 64 + bcol];
                acc[nt] = __builtin_amdgcn_mfma_f32_16x16x32_bf16(blh, th, acc[nt], 0, 0, 0);
                acc[nt] = __builtin_amdgcn_mfma_f32_16x16x32_bf16(bll, th, acc[nt], 0, 0, 0);
            }
        }
    } else {
        stageB(BdS, VeH);
        stageB(BdS + 8192, VeL);
        __syncthreads();
        #pragma unroll
        for (int kk = 0; kk < 2; kk++) {
            int bcol = (kk * 32 + quad * 8) ^ swzl;
            #pragma unroll
            for (int nt = 0; nt < 8; nt++) {
                s16x8 bh = *(const s16x8*)&BdS[(nt * 16 + l15) * 64 + bcol];
                s16x8 bl = *(const s16x8*)&BdS[8192 + (nt * 16 + l15) * 64 + bcol];
                acc[nt] = __builtin_amdgcn_mfma_f32_16x16x32_bf16(ahf[kk], bh, acc[nt], 0, 0, 0);
                acc[nt] = __builtin_amdgcn_mfma_f32_16x16x32_bf16(alf[kk], bh, acc[nt], 0, 0, 0);
                acc[nt] = __builtin_amdgcn_mfma_f32_16x16x32_bf16(ahf[kk], bl, acc[nt], 0, 0, 0);
            }
        }
        __syncthreads();
        stageB(BdS, TeH);
        stageB(BdS + 8192, TeL);
        __syncthreads();
        {
            int bcol = (quad * 8) ^ swzl;
            #pragma unroll
            for (int nt = 0; nt < 8; nt++) {
                s16x8 th = *(const s16x8*)&BdS[(nt * 16 + l15) * 64 + bcol];
                s16x8 tl = *(const s16x8*)&BdS[8192 + (nt * 16 + l15) * 64 + bcol];
                acc[nt] = __builtin_amdgcn_mfma_f32_16x16x32_bf16(blh, th, acc[nt], 0, 0, 0);
                acc[nt] = __builtin_amdgcn_mfma_f32_16x16x32_bf16(bll, th, acc[nt], 0, 0, 0);
                acc[nt] = __builtin_amdgcn_mfma_f32_16x16x32_bf16(blh, tl, acc[nt], 0, 0, 0);
            }
        }
    }
    __syncthreads();                   // Bd reads done before main loop staging

    // ---- P4: z epilogue -> Az hi/lo (paired cvt_pk u32 stores) ----
    #pragma unroll
    for (int r = 0; r < 4; r++) {
        int rloc = m0 + quad * 4 + r;
        int swr = (rloc & 7) * 8;
        #pragma unroll
        for (int nt = 0; nt < 8; nt++) {
            float val = acc[nt][r];
            float sx = __shfl_xor(val, 1);
            u32 w = cvtpk(val, sx);
            float res = val - bfbits2f(w & 0xffffu);
            float rx = __shfl_xor(res, 1);
            u32 wl = cvtpk(res, rx);
            if (!(l15 & 1)) {
                int colw = (nt * 16 + (l15 & ~1)) ^ swr;
                *(u32*)&Az_h[rloc * 128 + colw] = w;
                *(u32*)&Az_l[rloc * 128 + colw] = wl;
            }
        }
    }

    // ---- P5: mech x3 + QKV main loop (R3 structure) ----
    int shift = wexact ? 1 : 2;        // chunks per layer: 2 (hi) or 4 (hi+lo)
    int PER = 1 << shift;
    int NCH = 6 << shift;

    auto wchunk = [&](int ch) -> const u16* {
        int li = ch >> shift;
        int sub = ch & (PER - 1);
        int cc = sub & 1, lo = sub >> 1;
        const u16* p; size_t wb;
        if (li < 3)       { p = lo ? WmL : WmH; wb = (size_t)(v * NLL + li) * 16384; }
        else if (li == 3) { p = lo ? WqL : WqH; wb = (size_t)v * 16384; }
        else if (li == 4) { p = lo ? WkL : WkH; wb = (size_t)v * 16384; }
        else              { p = lo ? WvL : WvH; wb = (size_t)v * 16384; }
        return p + wb + cc * 8192;
    };

    auto epilogue = [&](int li) {
        float bcol[8], gcol[8], b2col[8];
        #pragma unroll
        for (int nt = 0; nt < 8; nt++) {
            int col = nt * 16 + l15;
            if (li < 3) {
                size_t pb = (size_t)v * (NLL * HH) + (size_t)li * HH + col;
                bcol[nt]  = ldf(mechb, pb, isbf);
                gcol[nt]  = ldf(lng, pb, isbf);
                b2col[nt] = ldf(lnb, pb, isbf);
            } else {
                const void* bp = (li == 3) ? bq : (li == 4) ? bk : bv;
                bcol[nt] = ldf(bp, (size_t)v * HH + col, isbf);
            }
        }
        if (li == 5) __syncthreads();   // claim Bd as V-transpose scratch
        #pragma unroll
        for (int r = 0; r < 4; r++) {
            float vals[8];
            float sum = 0.f, sq = 0.f;
            #pragma unroll
            for (int nt = 0; nt < 8; nt++) {
                float val = acc[nt][r] + bcol[nt];
                vals[nt] = val; sum += val; sq += val * val;
            }
            int rloc = m0 + quad * 4 + r;
            if (li < 3) {
                #pragma unroll
                for (int m = 1; m < 16; m <<= 1) {
                    sum += __shfl_xor(sum, m);
                    sq  += __shfl_xor(sq, m);
                }
                float mean = sum * (1.f / HH);
                float var  = sq * (1.f / HH) - mean * mean;
                float rstd = rsqrtf(var + 1e-5f);
                int swr = (rloc & 7) * 8;
                #pragma unroll
                for (int nt = 0; nt < 8; nt++) {
                    float y = (vals[nt] - mean) * rstd * gcol[nt] + b2col[nt];
                    y = 0.5f * y * (1.f + erff(y * 0.70710678118654752f));
                    float sx = __shfl_xor(y, 1);
                    u32 w = cvtpk(y, sx);
                    float res = y - bfbits2f(w & 0xffffu);
                    float rx = __shfl_xor(res, 1);
                    u32 wl = cvtpk(res, rx);
                    if (!(l15 & 1)) {
                        int colw = (nt * 16 + (l15 & ~1)) ^ swr;
                        *(u32*)&Az_h[rloc * 128 + colw] = w;
                        *(u32*)&Az_l[rloc * 128 + colw] = wl;
                    }
                }
            } else if (li == 3) {       // Q hi/lo: paired u32 stores
                int row = tile * 64 + rloc;
                size_t ob = ((size_t)v * BSZ + row) * HH;
                #pragma unroll
                for (int nt = 0; nt < 8; nt++) {
                    float val = vals[nt];
                    float sx = __shfl_xor(val, 1);
                    u32 w = cvtpk(val, sx);
                    float res = val - bfbits2f(w & 0xffffu);
                    float rx = __shfl_xor(res, 1);
                    u32 wl = cvtpk(res, rx);
                    if (!(l15 & 1)) {
                        size_t oi = ob + nt * 16 + (l15 & ~1);
                        *(u32*)&Qh[oi] = w;
                        *(u32*)&Ql[oi] = wl;
                    }
                }
            } else if (li == 4) {       // K: manual RNE, paired u32 stores
                int row = tile * 64 + rloc;
                size_t ob = ((size_t)v * BSZ + row) * HH;
                #pragma unroll
                for (int nt = 0; nt < 8; nt++) {
                    u32 h = f2bf(vals[nt]);
                    u32 hx = (u32)__shfl_xor((int)h, 1);
                    if (!(l15 & 1))
                        *(u32*)&Ko[ob + nt * 16 + (l15 & ~1)] = h | (hx << 16);
                }
            } else {                    // V: stage transposed tile in LDS
                #pragma unroll
                for (int nt = 0; nt < 8; nt++)
                    Vt_sh[(nt * 16 + l15) * PB + rloc] = f2bf(vals[nt]);
            }
        }
        if (li == 5) {
            __syncthreads();
            // coalesced V store: 128 (head,d) rows x 64 tt, full 64B lines
            int col = tid >> 1, half = tid & 1;
            int n = col >> 4, d = col & 15;
            int bb = tile >> 2, tq = (tile & 3) * 64;
            size_t dst = (((size_t)(v * BB + bb) * NHH + n) * DHH + d) * SS + tq + half * 32;
            #pragma unroll
            for (int j = 0; j < 4; j++)
                *(uint4*)&Vt[dst + j * 8] = *(const uint4*)&Vt_sh[col * PB + half * 32 + j * 8];
        }
    };

    stageB(BdS, wchunk(0));
    __syncthreads();

    for (int ch = 0; ch < NCH; ch++) {
        int bsel = ch & 1;
        if (ch + 1 < NCH) stageB(BdS + (bsel ^ 1) * 8192, wchunk(ch + 1));
        int sub = ch & (PER - 1);
        int li = ch >> shift;
        int cc = sub & 1, lo = sub >> 1;
        if (sub == 0) {
            #pragma unroll
            for (int nt = 0; nt < 8; nt++) {
                f32x4 zz = {0.f, 0.f, 0.f, 0.f};
                acc[nt] = zz;
            }
        }
        const u16* Bp = BdS + bsel * 8192;
        #pragma unroll
        for (int kk = 0; kk < 2; kk++) {
            int acol = (cc * 64 + kk * 32 + quad * 8) ^ swzl;
            int bcol = (kk * 32 + quad * 8) ^ swzl;
            s16x8 ah = *(const s16x8*)&Az_h[(m0 + l15) * 128 + acol];
            if (!lo) {
                s16x8 al = *(const s16x8*)&Az_l[(m0 + l15) * 128 + acol];
                #pragma unroll
                for (int nt = 0; nt < 8; nt++) {
                    s16x8 bh = *(const s16x8*)&Bp[(nt * 16 + l15) * 64 + bcol];
                    acc[nt] = __builtin_amdgcn_mfma_f32_16x16x32_bf16(ah, bh, acc[nt], 0, 0, 0);
                    acc[nt] = __builtin_amdgcn_mfma_f32_16x16x32_bf16(al, bh, acc[nt], 0, 0, 0);
                }
            } else {
                #pragma unroll
                for (int nt = 0; nt < 8; nt++) {
                    s16x8 bl = *(const s16x8*)&Bp[(nt * 16 + l15) * 64 + bcol];
                    acc[nt] = __builtin_amdgcn_mfma_f32_16x16x32_bf16(ah, bl, acc[nt], 0, 0, 0);
                }
            }
        }
        if (sub == PER - 1) epilogue(li);
        __syncthreads();
    }
}

// ---------------- kernel 5: MFMA attention, 4 waves / (v,b,head) -----------
#define LDW 40
__global__ __launch_bounds__(256) void k_attn2(const u16* __restrict__ Qh,
                                               const u16* __restrict__ Ql,
                                               const u16* __restrict__ K16,
                                               const u16* __restrict__ Vt,
                                               float* __restrict__ O) {
    __shared__ u16 Kp_sh[SS * LDW];        // 20 KB: cols 0-15 = K, 16-31 = K dup
    __shared__ u16 Vt_sh[DHH * 264];       // 8.25 KB
    __shared__ u16 P_sh[4][16 * LDW];      // per-wave P tile
    int tid = threadIdx.x;
    int wave = tid >> 6, lane = tid & 63;
    int quad = lane >> 4, l15 = lane & 15;
    int bn = blockIdx.x, v = blockIdx.y;
    int b = bn >> 3, n = bn & 7;
    size_t qkbase = ((size_t)v * BSZ + b * SS) * HH + n * DHH;
    size_t vtbase = ((size_t)(v * BB + b) * NHH + n) * DHH * SS;

    {
        int row = tid;
        uint4 k0 = *(const uint4*)&K16[qkbase + (size_t)row * HH];
        uint4 k1 = *(const uint4*)&K16[qkbase + (size_t)row * HH + 8];
        *(uint4*)&Kp_sh[row * LDW + 0]  = k0;
        *(uint4*)&Kp_sh[row * LDW + 8]  = k1;
        *(uint4*)&Kp_sh[row * LDW + 16] = k0;
        *(uint4*)&Kp_sh[row * LDW + 24] = k1;
    }
    #pragma unroll
    for (int u = 0; u < 2; u++) {
        int p = u * 256 + tid;
        int d = p >> 5, su = (p & 31) * 8;
        *(uint4*)&Vt_sh[d * 264 + su] = *(const uint4*)&Vt[vtbase + (size_t)d * SS + su];
    }
    __syncthreads();

    s16x8 ones;
    #pragma unroll
    for (int i = 0; i < 8; i++) ones[i] = (short)0x3F80;

    for (int mt = wave * 4; mt < wave * 4 + 4; mt++) {
        const u16* Qsrc = (quad < 2) ? Qh : Ql;
        s16x8 aq = *(const s16x8*)&Qsrc[qkbase + (size_t)(mt * 16 + l15) * HH + (quad & 1) * 8];
        f32x4 oacc = {0.f, 0.f, 0.f, 0.f};
        f32x4 lacc = {0.f, 0.f, 0.f, 0.f};
        for (int jt2 = 0; jt2 < 8; jt2++) {
            #pragma unroll
            for (int sub = 0; sub < 2; sub++) {
                int jt = jt2 * 2 + sub;
                s16x8 bk = *(const s16x8*)&Kp_sh[(jt * 16 + l15) * LDW + quad * 8];
                f32x4 s = {0.f, 0.f, 0.f, 0.f};
                s = __builtin_amdgcn_mfma_f32_16x16x32_bf16(aq, bk, s, 0, 0, 0);
                #pragma unroll
                for (int r = 0; r < 4; r++) {
                    float p = __expf(s[r] * 0.25f);
                    P_sh[wave][(quad * 4 + r) * LDW + sub * 16 + l15] = f2bf_trunc(p);
                }
            }
            s16x8 ap = *(const s16x8*)&P_sh[wave][l15 * LDW + quad * 8];
            s16x8 bv = *(const s16x8*)&Vt_sh[l15 * 264 + jt2 * 32 + quad * 8];
            oacc = __builtin_amdgcn_mfma_f32_16x16x32_bf16(ap, bv, oacc, 0, 0, 0);
            lacc = __builtin_amdgcn_mfma_f32_16x16x32_bf16(ap, ones, lacc, 0, 0, 0);
        }
        #pragma unroll
        for (int r = 0; r < 4; r++) {
            float val = oacc[r] / lacc[r];
            O[((size_t)v * BSZ + b * SS + mt * 16 + quad * 4 + r) * HH + n * DHH + l15] = val;
        }
    }
}

// ---------------- kernel 6: fused output head (coalesced) ------------------
__global__ __launch_bounds__(256) void k_final(const float* __restrict__ o,
                                               const float* __restrict__ wfused,
                                               const float* __restrict__ bfused,
                                               void* __restrict__ out,
                                               const int* __restrict__ flags) {
    __shared__ float wf[HH];
    int isbf = flags[0];
    int tid = threadIdx.x; int b = blockIdx.x; int v = blockIdx.y;
    if (tid < HH) wf[tid] = wfused[v * HH + tid];
    __syncthreads();
    int rg = tid >> 3;
    int l8 = tid & 7;
    float4 w0 = *(const float4*)&wf[l8 * 16];
    float4 w1 = *(const float4*)&wf[l8 * 16 + 4];
    float4 w2 = *(const float4*)&wf[l8 * 16 + 8];
    float4 w3 = *(const float4*)&wf[l8 * 16 + 12];
    float bv = bfused[v];
    #pragma unroll
    for (int pass = 0; pass < 8; pass++) {
        int bt = b * SS + pass * 32 + rg;
        const float4* orow = (const float4*)(o + ((size_t)v * BSZ + bt) * HH + l8 * 16);
        float4 a0 = orow[0], a1 = orow[1], a2 = orow[2], a3 = orow[3];
        float acc = a0.x * w0.x + a0.y * w0.y + a0.z * w0.z + a0.w * w0.w
                  + a1.x * w1.x + a1.y * w1.y + a1.z * w1.z + a1.w * w1.w
                  + a2.x * w2.x + a2.y * w2.y + a2.z * w2.z + a2.w * w2.w
                  + a3.x * w3.x + a3.y * w3.y + a3.z * w3.z + a3.w * w3.w;
        acc += __shfl_xor(acc, 1);
        acc += __shfl_xor(acc, 2);
        acc += __shfl_xor(acc, 4);
        if (l8 == 0) {
            float pred = acc + bv;
            size_t oi = (size_t)bt * VV + v;
            if (isbf) ((u16*)out)[oi] = f2bf(pred);
            else      ((float*)out)[oi] = pred;
        }
    }
}

extern "C" void kernel_launch(void* const* d_in, const int* in_sizes, int n_in,
                              void* d_out, int out_size, void* d_ws, size_t ws_size,
                              hipStream_t stream) {
    (void)out_size; (void)ws_size;

    // ---- resolve input permutation from in_sizes (host-side, capture-safe) ----
    static const int dict_sizes[18]  = {65536,45056,8192,1408,3145728,24576,24576,24576,
                                        1048576,1048576,1048576,1048576,8192,8192,8192,8192,8192,64};
    static const int alpha_sizes[18] = {1048576,1048576,1048576,1048576,45056,8192,8192,8192,
                                        8192,24576,24576,3145728,24576,8192,64,1408,8192,65536};
    static const int alpha_pos[18]   = {17,4,16,15,11,12,10,9,2,0,3,1,7,5,8,6,13,14};
    static const int alpha_logical[18] = {9,11,8,10,1,13,15,12,14,7,6,4,5,16,17,3,2,0};

    const void* in[18];
    bool is_dict = (n_in == 18), is_alpha = (n_in == 18);
    for (int i = 0; i < 18 && i < n_in; i++) {
        if (in_sizes[i] != dict_sizes[i])  is_dict = false;
        if (in_sizes[i] != alpha_sizes[i]) is_alpha = false;
    }
    if (is_dict) {
        for (int i = 0; i < 18; i++) in[i] = d_in[i];
    } else if (is_alpha) {
        for (int i = 0; i < 18; i++) in[i] = d_in[alpha_pos[i]];
    } else {
        bool used[18] = {false};
        for (int a = 0; a < 18; a++) {
            int lg = alpha_logical[a];
            for (int i = 0; i < n_in && i < 18; i++) {
                if (!used[i] && in_sizes[i] == dict_sizes[lg]) {
                    in[lg] = d_in[i]; used[i] = true; break;
                }
            }
        }
    }

    const void* x        = in[0];
    const void* adjl     = in[1];
    const void* var_emb  = in[2];
    const void* temp_emb = in[3];
    const void* mechW    = in[4];
    const void* mechb    = in[5];
    const void* lng      = in[6];
    const void* lnb      = in[7];
    const void* Wq       = in[8];
    const void* Wk       = in[9];
    const void* Wv       = in[10];
    const void* Wo       = in[11];
    const void* bq       = in[12];
    const void* bk       = in[13];
    const void* bv       = in[14];
    const void* bo       = in[15];
    const void* outW     = in[16];
    const void* outb     = in[17];

    // workspace (f32-unit offsets); ws is ~256 MB (fillBuffer evidence, R2)
    float* ws     = (float*)d_ws;
    int*   flags  = (int*)ws;                   // 32 f
    float* adj    = ws + 32;                    // 45056
    float* wfused = ws + 45088;                 // 8192
    float* bfused = ws + 53280;                 // 64 (to 53376)
    float* Obuf   = ws + 53376;                 // attn output (fp32, 33.5 MB)
    u16*   zhB    = (u16*)(ws + 8441984);       // Q hi
    u16*   zlB    = (u16*)(ws + 12636288);      // Q lo
    u16*   K16    = (u16*)(ws + 16830592);      // -> 21024896
    u16*   Vt16   = (u16*)(ws + 21024896);      // -> 25219200
    u16*   WtmH   = (u16*)(ws + 25219200);      // -> 26792064
    u16*   WtmL   = (u16*)(ws + 26792064);      // -> 28364928
    u16*   WtqH   = (u16*)(ws + 28364928);      // -> 28889216
    u16*   WtqL   = (u16*)(ws + 28889216);      // -> 29413504
    u16*   WtkH   = (u16*)(ws + 29413504);      // -> 29937792
    u16*   WtkL   = (u16*)(ws + 29937792);      // -> 30462080
    u16*   WtvH   = (u16*)(ws + 30462080);      // -> 30986368
    u16*   WtvL   = (u16*)(ws + 30986368);      // -> 31510656
    u16*   WveH   = (u16*)(ws + 31510656);      // 8192 u16
    u16*   WveL   = (u16*)(ws + 31514752);
    u16*   WteH   = (u16*)(ws + 31518848);
    u16*   WteL   = (u16*)(ws + 31522944);      // ends 31527040

    k_sniff <<<dim3(1),    dim3(64),  0, stream>>>((const u16*)mechW, flags);
    k_adj   <<<dim3(176),  dim3(256), 0, stream>>>(adjl, adj, flags);
    k_fuse  <<<dim3(64),   dim3(128), 0, stream>>>(Wo, outW, bo, outb, wfused, bfused, flags);

    WPack wp;
    wp.src[0] = mechW;    wp.dh[0] = WtmH; wp.dl[0] = WtmL;
    wp.src[1] = Wq;       wp.dh[1] = WtqH; wp.dl[1] = WtqL;
    wp.src[2] = Wk;       wp.dh[2] = WtkH; wp.dl[2] = WtkL;
    wp.src[3] = Wv;       wp.dh[3] = WtvH; wp.dl[3] = WtvL;
    wp.src[4] = var_emb;  wp.dh[4] = WveH; wp.dl[4] = WveL;
    wp.src[5] = temp_emb; wp.dh[5] = WteH; wp.dl[5] = WteL;
    k_wprep <<<dim3(386),  dim3(256), 0, stream>>>(wp, flags);

    // fully fused: causal + mech x3 + QKV (k_causal is gone)
    k_mega<<<dim3(1024), dim3(256), 0, stream>>>(
            x, adj,
            WveH, WveL, WteH, WteL,
            WtmH, WtmL, WtqH, WtqL, WtkH, WtkL, WtvH, WtvL,
            mechb, lng, lnb, bq, bk, bv,
            zhB, zlB, K16, Vt16, flags);

    k_attn2 <<<dim3(BB * NHH, VV), dim3(256), 0, stream>>>(zhB, zlB, K16, Vt16, Obuf);
    k_final <<<dim3(BB, VV), dim3(256), 0, stream>>>(Obuf, wfused, bfused, d_out, flags);
}